// Round 1
// baseline (117.936 us; speedup 1.0000x reference)
//
#include <hip/hip_runtime.h>
#include <stdint.h>

typedef unsigned short u16;
typedef __attribute__((ext_vector_type(8))) __bf16 bf16x8;
typedef __attribute__((ext_vector_type(4))) float f32x4;

#define S_LEN 2048
#define EMB   1024
#define NH    16
#define NKV   4
#define HD    64
#define WIN   256
#define NB    2
#define MROWS (NB * S_LEN)   // 4096

// ---------- helpers ----------
__device__ __forceinline__ u16 f2bf(float f) {
    uint32_t u = __float_as_uint(f);
    uint32_t r = (u + 0x7FFFu + ((u >> 16) & 1u)) >> 16;   // RNE
    return (u16)r;
}

__device__ __forceinline__ void gload16(const void* g, void* l) {
    // async global->LDS, 16B per lane; LDS dest = wave-uniform base + lane*16
    __builtin_amdgcn_global_load_lds(
        (const __attribute__((address_space(1))) uint32_t*)(uintptr_t)g,
        (__attribute__((address_space(3))) uint32_t*)(uintptr_t)l,
        16, 0, 0);
}

// ---------- conversion kernels ----------
__global__ __launch_bounds__(256) void cvt_kernel(const float* __restrict__ in,
                                                  u16* __restrict__ out, int n8) {
    int i = blockIdx.x * blockDim.x + threadIdx.x;
    if (i >= n8) return;
    const float4* p = (const float4*)in + (size_t)i * 2;
    float4 a = p[0], b = p[1];
    uint4 q;
    q.x = f2bf(a.x) | ((uint32_t)f2bf(a.y) << 16);
    q.y = f2bf(a.z) | ((uint32_t)f2bf(a.w) << 16);
    q.z = f2bf(b.x) | ((uint32_t)f2bf(b.y) << 16);
    q.w = f2bf(b.z) | ((uint32_t)f2bf(b.w) << 16);
    ((uint4*)out)[i] = q;
}

// in [R][C] f32  ->  out [C][R] bf16
__global__ __launch_bounds__(256) void transpose_cvt_kernel(const float* __restrict__ in,
                                                            u16* __restrict__ out,
                                                            int R, int C) {
    __shared__ float t[32][33];
    int c0 = blockIdx.x * 32, r0 = blockIdx.y * 32;
    int tx = threadIdx.x, ty = threadIdx.y;   // (32, 8)
#pragma unroll
    for (int j = 0; j < 32; j += 8)
        t[ty + j][tx] = in[(size_t)(r0 + ty + j) * C + (c0 + tx)];
    __syncthreads();
#pragma unroll
    for (int j = 0; j < 32; j += 8)
        out[(size_t)(c0 + ty + j) * R + (r0 + tx)] = f2bf(t[tx][ty + j]);
}

// ---------- GEMM core: C[128x128] tile, A[M][K] bf16 row-major, Bt[N][K] bf16 row-major ----------
// block = 256 threads = 4 waves (2x2), wave -> 64x64 out, 16x16x32 MFMA
__device__ __forceinline__ void gemm_core(const u16* __restrict__ A, const u16* __restrict__ Bt,
                                          int K, int m0, int n0r,
                                          u16* As, u16* Bs, f32x4 (&acc)[4][4], int tid) {
    const int lane = tid & 63, w = tid >> 6;
    const int wr = w >> 1, wc = w & 1;
    const int r = lane & 15, g = lane >> 4;

    for (int k0 = 0; k0 < K; k0 += 64) {
#pragma unroll
        for (int i = 0; i < 4; ++i) {
            int cb = i * 256 + w * 64;        // wave-uniform chunk base
            int chunk = cb + lane;
            int row = chunk >> 3, cc = chunk & 7;
            gload16(A + (size_t)(m0 + row) * K + k0 + cc * 8, As + cb * 8);
            gload16(Bt + (size_t)(n0r + row) * K + k0 + cc * 8, Bs + cb * 8);
        }
        __syncthreads();
        bf16x8 af[4][2], bfr[4][2];
#pragma unroll
        for (int mf = 0; mf < 4; ++mf)
#pragma unroll
            for (int kk = 0; kk < 2; ++kk)
                af[mf][kk] = *(const bf16x8*)(As + (wr * 64 + mf * 16 + r) * 64 + kk * 32 + g * 8);
#pragma unroll
        for (int nf = 0; nf < 4; ++nf)
#pragma unroll
            for (int kk = 0; kk < 2; ++kk)
                bfr[nf][kk] = *(const bf16x8*)(Bs + (wc * 64 + nf * 16 + r) * 64 + kk * 32 + g * 8);
#pragma unroll
        for (int mf = 0; mf < 4; ++mf)
#pragma unroll
            for (int nf = 0; nf < 4; ++nf)
#pragma unroll
                for (int kk = 0; kk < 2; ++kk)
                    acc[mf][nf] = __builtin_amdgcn_mfma_f32_16x16x32_bf16(
                        af[mf][kk], bfr[nf][kk], acc[mf][nf], 0, 0, 0);
        __syncthreads();
    }
}

// ---------- QKV projection ----------
// grid (12, 32): nt 0-7 -> Q, 8-9 -> K, 10-11 -> V
__global__ __launch_bounds__(256) void gemm_qkv_kernel(
    const u16* __restrict__ xb, const u16* __restrict__ wqt,
    const u16* __restrict__ wkt, const u16* __restrict__ wvt,
    const float* __restrict__ bq, const float* __restrict__ bk, const float* __restrict__ bv,
    u16* __restrict__ Qb, u16* __restrict__ Kb, u16* __restrict__ Vt) {
    __shared__ __align__(16) u16 As[128 * 64];
    __shared__ __align__(16) u16 Bs[128 * 64];
    int tid = threadIdx.x;
    int n0 = blockIdx.x * 128, m0 = blockIdx.y * 128;

    const u16* Bt; int n0r; const float* bias; int mode;
    if (n0 < 1024)      { Bt = wqt; n0r = n0;        bias = bq; mode = 0; }
    else if (n0 < 1280) { Bt = wkt; n0r = n0 - 1024; bias = bk; mode = 1; }
    else                { Bt = wvt; n0r = n0 - 1280; bias = bv; mode = 2; }

    f32x4 acc[4][4];
    f32x4 z = {0.f, 0.f, 0.f, 0.f};
#pragma unroll
    for (int i = 0; i < 4; ++i)
#pragma unroll
        for (int j = 0; j < 4; ++j) acc[i][j] = z;

    gemm_core(xb, Bt, EMB, m0, n0r, As, Bs, acc, tid);

    const int lane = tid & 63, w = tid >> 6;
    const int wr = w >> 1, wc = w & 1, r = lane & 15, g = lane >> 4;
#pragma unroll
    for (int nf = 0; nf < 4; ++nf) {
        int nn = n0r + wc * 64 + nf * 16 + r;   // col within this weight's N
        float bb = bias[nn];
        int hh = nn >> 6, dd = nn & 63;
#pragma unroll
        for (int mf = 0; mf < 4; ++mf)
#pragma unroll
            for (int reg = 0; reg < 4; ++reg) {
                int m = m0 + wr * 64 + mf * 16 + g * 4 + reg;
                int b = m >> 11, s = m & 2047;
                u16 o = f2bf(acc[mf][nf][reg] + bb);
                if (mode == 0)
                    Qb[((size_t)(b * NH + hh) * S_LEN + s) * HD + dd] = o;
                else if (mode == 1)
                    Kb[((size_t)(b * NKV + hh) * S_LEN + s) * HD + dd] = o;
                else
                    Vt[((size_t)(b * NKV + hh) * HD + dd) * S_LEN + s] = o;  // V transposed [D][S]
            }
    }
}

// ---------- sliding-window flash attention ----------
// grid (32, 16, 2); block 256 = 4 waves; wave = 16 query rows; key tiles of 64
__global__ __launch_bounds__(256) void attn_kernel(const u16* __restrict__ Qb,
                                                   const u16* __restrict__ Kb,
                                                   const u16* __restrict__ Vt,
                                                   u16* __restrict__ ctx) {
    __shared__ __align__(16) u16 Plds[4][16 * 72];   // per-wave P buffer, padded rows
    const int tid = threadIdx.x;
    const int lane = tid & 63, w = tid >> 6;
    const int r = lane & 15, g = lane >> 4;
    const int q0 = blockIdx.x * 64;
    const int h = blockIdx.y, b = blockIdx.z;
    const int kvh = h >> 2;                          // consecutive repeat_kv
    const u16* Qw = Qb + ((size_t)(b * NH + h) * S_LEN + q0 + w * 16) * HD;
    const u16* Kh = Kb + (size_t)(b * NKV + kvh) * S_LEN * HD;
    const u16* Vh = Vt + (size_t)(b * NKV + kvh) * HD * S_LEN;
    u16* Pw = &Plds[w][0];

    bf16x8 qf[2];
#pragma unroll
    for (int kk = 0; kk < 2; ++kk)
        qf[kk] = *(const bf16x8*)(Qw + r * 64 + kk * 32 + g * 8);

    f32x4 o[4];
    float mrow[4], lrow[4];
    f32x4 z = {0.f, 0.f, 0.f, 0.f};
#pragma unroll
    for (int i = 0; i < 4; ++i) { o[i] = z; }
#pragma unroll
    for (int reg = 0; reg < 4; ++reg) { mrow[reg] = -30000.0f; lrow[reg] = 0.0f; }

    int iq[4];
#pragma unroll
    for (int reg = 0; reg < 4; ++reg) iq[reg] = q0 + w * 16 + g * 4 + reg;

    const float LOG2E = 1.4426950408889634f;
    int kt0 = (q0 >= 256) ? 0 : (256 - q0) / 64;
    for (int kt = kt0; kt < 5; ++kt) {
        int kbase = q0 - 256 + kt * 64;              // >= 0 by construction
        f32x4 sa[4];
#pragma unroll
        for (int nf = 0; nf < 4; ++nf) sa[nf] = z;
#pragma unroll
        for (int nf = 0; nf < 4; ++nf)
#pragma unroll
            for (int kk = 0; kk < 2; ++kk) {
                bf16x8 kf = *(const bf16x8*)(Kh + (size_t)(kbase + nf * 16 + r) * HD + kk * 32 + g * 8);
                sa[nf] = __builtin_amdgcn_mfma_f32_16x16x32_bf16(qf[kk], kf, sa[nf], 0, 0, 0);
            }
        // scale + mask; lane holds rows g*4+reg, key col = kbase + nf*16 + r
        float p[4][4];
        float tmax[4] = {-1e30f, -1e30f, -1e30f, -1e30f};
#pragma unroll
        for (int nf = 0; nf < 4; ++nf) {
            int j = kbase + nf * 16 + r;
#pragma unroll
            for (int reg = 0; reg < 4; ++reg) {
                float x = sa[nf][reg] * 0.125f;
                bool valid = (j <= iq[reg]) && (iq[reg] - j <= WIN);
                x = valid ? x : -1e30f;
                p[nf][reg] = x;
                tmax[reg] = fmaxf(tmax[reg], x);
            }
        }
#pragma unroll
        for (int off = 1; off < 16; off <<= 1)
#pragma unroll
            for (int reg = 0; reg < 4; ++reg)
                tmax[reg] = fmaxf(tmax[reg], __shfl_xor(tmax[reg], off, 64));

        float alpha[4], psum[4];
#pragma unroll
        for (int reg = 0; reg < 4; ++reg) {
            float mnew = fmaxf(mrow[reg], tmax[reg]);   // mrow init -3e4 keeps mnew sane
            alpha[reg] = exp2f((mrow[reg] - mnew) * LOG2E);
            mrow[reg] = mnew;
            psum[reg] = 0.f;
        }
#pragma unroll
        for (int nf = 0; nf < 4; ++nf)
#pragma unroll
            for (int reg = 0; reg < 4; ++reg) {
                float e = exp2f((p[nf][reg] - mrow[reg]) * LOG2E);
                p[nf][reg] = e;
                psum[reg] += e;
            }
#pragma unroll
        for (int off = 1; off < 16; off <<= 1)
#pragma unroll
            for (int reg = 0; reg < 4; ++reg)
                psum[reg] += __shfl_xor(psum[reg], off, 64);
#pragma unroll
        for (int reg = 0; reg < 4; ++reg)
            lrow[reg] = lrow[reg] * alpha[reg] + psum[reg];
#pragma unroll
        for (int nf2 = 0; nf2 < 4; ++nf2)
#pragma unroll
            for (int reg = 0; reg < 4; ++reg)
                o[nf2][reg] *= alpha[reg];

        // P -> LDS (bf16), re-layout for PV A-fragments
#pragma unroll
        for (int nf = 0; nf < 4; ++nf)
#pragma unroll
            for (int reg = 0; reg < 4; ++reg)
                Pw[(g * 4 + reg) * 72 + nf * 16 + r] = f2bf(p[nf][reg]);

#pragma unroll
        for (int kk2 = 0; kk2 < 2; ++kk2) {
            bf16x8 pa = *(const bf16x8*)(Pw + r * 72 + kk2 * 32 + g * 8);
#pragma unroll
            for (int nf2 = 0; nf2 < 4; ++nf2) {
                bf16x8 vb = *(const bf16x8*)(Vh + (size_t)(nf2 * 16 + r) * S_LEN + kbase + kk2 * 32 + g * 8);
                o[nf2] = __builtin_amdgcn_mfma_f32_16x16x32_bf16(pa, vb, o[nf2], 0, 0, 0);
            }
        }
    }

    // finalize: ctx[b][s][h*64+d] bf16
#pragma unroll
    for (int nf2 = 0; nf2 < 4; ++nf2) {
        int dcol = h * 64 + nf2 * 16 + r;
#pragma unroll
        for (int reg = 0; reg < 4; ++reg) {
            int s = q0 + w * 16 + g * 4 + reg;
            ctx[((size_t)(b * S_LEN + s)) * EMB + dcol] = f2bf(o[nf2][reg] / lrow[reg]);
        }
    }
}

// ---------- output projection ----------
__global__ __launch_bounds__(256) void gemm_out_kernel(const u16* __restrict__ ctxb,
                                                       const u16* __restrict__ wot,
                                                       const float* __restrict__ bo,
                                                       float* __restrict__ out) {
    __shared__ __align__(16) u16 As[128 * 64];
    __shared__ __align__(16) u16 Bs[128 * 64];
    int tid = threadIdx.x;
    int n0 = blockIdx.x * 128, m0 = blockIdx.y * 128;

    f32x4 acc[4][4];
    f32x4 z = {0.f, 0.f, 0.f, 0.f};
#pragma unroll
    for (int i = 0; i < 4; ++i)
#pragma unroll
        for (int j = 0; j < 4; ++j) acc[i][j] = z;

    gemm_core(ctxb, wot, EMB, m0, n0, As, Bs, acc, tid);

    const int lane = tid & 63, w = tid >> 6;
    const int wr = w >> 1, wc = w & 1, r = lane & 15, g = lane >> 4;
#pragma unroll
    for (int nf = 0; nf < 4; ++nf) {
        int n = n0 + wc * 64 + nf * 16 + r;
        float bb = bo[n];
#pragma unroll
        for (int mf = 0; mf < 4; ++mf)
#pragma unroll
            for (int reg = 0; reg < 4; ++reg) {
                int m = m0 + wr * 64 + mf * 16 + g * 4 + reg;
                out[(size_t)m * EMB + n] = acc[mf][nf][reg] + bb;
            }
    }
}

// ---------- launch ----------
extern "C" void kernel_launch(void* const* d_in, const int* in_sizes, int n_in,
                              void* d_out, int out_size, void* d_ws, size_t ws_size,
                              hipStream_t stream) {
    const float* x  = (const float*)d_in[0];
    const float* wq = (const float*)d_in[1];
    const float* bq = (const float*)d_in[2];
    const float* wk = (const float*)d_in[3];
    const float* bk = (const float*)d_in[4];
    const float* wv = (const float*)d_in[5];
    const float* bv = (const float*)d_in[6];
    const float* wo = (const float*)d_in[7];
    const float* bo = (const float*)d_in[8];
    float* out = (float*)d_out;

    char* ws = (char*)d_ws;
    u16* xb  = (u16*)ws;                 ws += (size_t)MROWS * EMB * 2;         // 8 MB
    u16* wqt = (u16*)ws;                 ws += (size_t)EMB * EMB * 2;           // 2 MB
    u16* wkt = (u16*)ws;                 ws += (size_t)256 * EMB * 2;           // 0.5 MB
    u16* wvt = (u16*)ws;                 ws += (size_t)256 * EMB * 2;           // 0.5 MB
    u16* wot = (u16*)ws;                 ws += (size_t)EMB * EMB * 2;           // 2 MB
    u16* Qb  = (u16*)ws;                 ws += (size_t)NB * NH * S_LEN * HD * 2;  // 8 MB
    u16* Kb  = (u16*)ws;                 ws += (size_t)NB * NKV * S_LEN * HD * 2; // 2 MB
    u16* Vt  = (u16*)ws;                 ws += (size_t)NB * NKV * S_LEN * HD * 2; // 2 MB
    u16* ctx = (u16*)ws;                 ws += (size_t)MROWS * EMB * 2;         // 8 MB

    cvt_kernel<<<2048, 256, 0, stream>>>(x, xb, (MROWS * EMB) / 8);
    transpose_cvt_kernel<<<dim3(32, 32), dim3(32, 8), 0, stream>>>(wq, wqt, EMB, EMB);
    transpose_cvt_kernel<<<dim3(8, 32),  dim3(32, 8), 0, stream>>>(wk, wkt, EMB, 256);
    transpose_cvt_kernel<<<dim3(8, 32),  dim3(32, 8), 0, stream>>>(wv, wvt, EMB, 256);
    transpose_cvt_kernel<<<dim3(32, 32), dim3(32, 8), 0, stream>>>(wo, wot, EMB, EMB);

    gemm_qkv_kernel<<<dim3(12, 32), 256, 0, stream>>>(xb, wqt, wkt, wvt, bq, bk, bv, Qb, Kb, Vt);
    attn_kernel<<<dim3(32, 16, 2), 256, 0, stream>>>(Qb, Kb, Vt, ctx);
    gemm_out_kernel<<<dim3(8, 32), 256, 0, stream>>>(ctx, wot, bo, out);
}

// Round 2
// 113.739 us; speedup vs baseline: 1.0369x; 1.0369x over previous
//
#include <hip/hip_runtime.h>
#include <stdint.h>

typedef unsigned short u16;
typedef __attribute__((ext_vector_type(8))) __bf16 bf16x8;
typedef __attribute__((ext_vector_type(4))) __bf16 bf16x4;
typedef __attribute__((ext_vector_type(4))) float f32x4;

#define S_LEN 2048
#define EMB   1024
#define NH    16
#define NKV   4
#define HD    64
#define WIN   256
#define NB    2
#define MROWS (NB * S_LEN)   // 4096

// ---------- helpers ----------
__device__ __forceinline__ u16 f2bf(float f) {
    uint32_t u = __float_as_uint(f);
    uint32_t r = (u + 0x7FFFu + ((u >> 16) & 1u)) >> 16;   // RNE
    return (u16)r;
}

__device__ __forceinline__ float fast_exp2(float x) {
#if __has_builtin(__builtin_amdgcn_exp2f)
    return __builtin_amdgcn_exp2f(x);
#else
    float r; asm("v_exp_f32 %0, %1" : "=v"(r) : "v"(x)); return r;
#endif
}

__device__ __forceinline__ void gload16(const void* g, void* l) {
    __builtin_amdgcn_global_load_lds(
        (const __attribute__((address_space(1))) uint32_t*)(uintptr_t)g,
        (__attribute__((address_space(3))) uint32_t*)(uintptr_t)l,
        16, 0, 0);
}

// ---------- conversion kernels ----------
__global__ __launch_bounds__(256) void cvt_kernel(const float* __restrict__ in,
                                                  u16* __restrict__ out, int n8) {
    int i = blockIdx.x * blockDim.x + threadIdx.x;
    if (i >= n8) return;
    const float4* p = (const float4*)in + (size_t)i * 2;
    float4 a = p[0], b = p[1];
    uint4 q;
    q.x = f2bf(a.x) | ((uint32_t)f2bf(a.y) << 16);
    q.y = f2bf(a.z) | ((uint32_t)f2bf(a.w) << 16);
    q.z = f2bf(b.x) | ((uint32_t)f2bf(b.y) << 16);
    q.w = f2bf(b.z) | ((uint32_t)f2bf(b.w) << 16);
    ((uint4*)out)[i] = q;
}

// in [R][C] f32  ->  out [C][R] bf16
__global__ __launch_bounds__(256) void transpose_cvt_kernel(const float* __restrict__ in,
                                                            u16* __restrict__ out,
                                                            int R, int C) {
    __shared__ float t[32][33];
    int c0 = blockIdx.x * 32, r0 = blockIdx.y * 32;
    int tx = threadIdx.x, ty = threadIdx.y;   // (32, 8)
#pragma unroll
    for (int j = 0; j < 32; j += 8)
        t[ty + j][tx] = in[(size_t)(r0 + ty + j) * C + (c0 + tx)];
    __syncthreads();
#pragma unroll
    for (int j = 0; j < 32; j += 8)
        out[(size_t)(c0 + ty + j) * R + (r0 + tx)] = f2bf(t[tx][ty + j]);
}

// ---------- GEMM core ----------
__device__ __forceinline__ void gemm_core(const __bf16* __restrict__ A, const __bf16* __restrict__ Bt,
                                          int K, int m0, int n0r,
                                          __bf16* As, __bf16* Bs, f32x4 (&acc)[4][4], int tid) {
    const int lane = tid & 63, w = tid >> 6;
    const int wr = w >> 1, wc = w & 1;
    const int r = lane & 15, g = lane >> 4;

    for (int k0 = 0; k0 < K; k0 += 64) {
#pragma unroll
        for (int i = 0; i < 4; ++i) {
            int cb = i * 256 + w * 64;        // wave-uniform chunk base
            int chunk = cb + lane;
            int row = chunk >> 3, cc = chunk & 7;
            gload16(A + (size_t)(m0 + row) * K + k0 + cc * 8, As + cb * 8);
            gload16(Bt + (size_t)(n0r + row) * K + k0 + cc * 8, Bs + cb * 8);
        }
        __syncthreads();
        bf16x8 af[4][2], bfr[4][2];
#pragma unroll
        for (int mf = 0; mf < 4; ++mf)
#pragma unroll
            for (int kk = 0; kk < 2; ++kk)
                af[mf][kk] = *(const bf16x8*)(As + (wr * 64 + mf * 16 + r) * 64 + kk * 32 + g * 8);
#pragma unroll
        for (int nf = 0; nf < 4; ++nf)
#pragma unroll
            for (int kk = 0; kk < 2; ++kk)
                bfr[nf][kk] = *(const bf16x8*)(Bs + (wc * 64 + nf * 16 + r) * 64 + kk * 32 + g * 8);
#pragma unroll
        for (int mf = 0; mf < 4; ++mf)
#pragma unroll
            for (int nf = 0; nf < 4; ++nf)
#pragma unroll
                for (int kk = 0; kk < 2; ++kk)
                    acc[mf][nf] = __builtin_amdgcn_mfma_f32_16x16x32_bf16(
                        af[mf][kk], bfr[nf][kk], acc[mf][nf], 0, 0, 0);
        __syncthreads();
    }
}

// ---------- QKV projection ----------
__global__ __launch_bounds__(256) void gemm_qkv_kernel(
    const __bf16* __restrict__ xb, const __bf16* __restrict__ wqt,
    const __bf16* __restrict__ wkt, const __bf16* __restrict__ wvt,
    const float* __restrict__ bq, const float* __restrict__ bk, const float* __restrict__ bv,
    __bf16* __restrict__ Qb, __bf16* __restrict__ Kb, __bf16* __restrict__ Vt) {
    __shared__ __align__(16) __bf16 As[128 * 64];
    __shared__ __align__(16) __bf16 Bs[128 * 64];
    int tid = threadIdx.x;
    int n0 = blockIdx.x * 128, m0 = blockIdx.y * 128;

    const __bf16* Bt; int n0r; const float* bias; int mode;
    if (n0 < 1024)      { Bt = wqt; n0r = n0;        bias = bq; mode = 0; }
    else if (n0 < 1280) { Bt = wkt; n0r = n0 - 1024; bias = bk; mode = 1; }
    else                { Bt = wvt; n0r = n0 - 1280; bias = bv; mode = 2; }

    f32x4 acc[4][4];
    f32x4 z = {0.f, 0.f, 0.f, 0.f};
#pragma unroll
    for (int i = 0; i < 4; ++i)
#pragma unroll
        for (int j = 0; j < 4; ++j) acc[i][j] = z;

    gemm_core(xb, Bt, EMB, m0, n0r, As, Bs, acc, tid);

    const int lane = tid & 63, w = tid >> 6;
    const int wr = w >> 1, wc = w & 1, r = lane & 15, g = lane >> 4;
#pragma unroll
    for (int nf = 0; nf < 4; ++nf) {
        int nn = n0r + wc * 64 + nf * 16 + r;
        float bb = bias[nn];
        int hh = nn >> 6, dd = nn & 63;
        if (mode == 2) {
            // V transposed [D][S]: regs -> consecutive s, pack 4 bf16 = 8B store
#pragma unroll
            for (int mf = 0; mf < 4; ++mf) {
                int s0 = m0 + wr * 64 + mf * 16 + g * 4;
                int bi = s0 >> 11, s = s0 & 2047;
                bf16x4 pk;
#pragma unroll
                for (int reg = 0; reg < 4; ++reg) pk[reg] = (__bf16)(acc[mf][nf][reg] + bb);
                *reinterpret_cast<bf16x4*>(Vt + ((size_t)(bi * NKV + hh) * HD + dd) * S_LEN + s) = pk;
            }
        } else {
#pragma unroll
            for (int mf = 0; mf < 4; ++mf)
#pragma unroll
                for (int reg = 0; reg < 4; ++reg) {
                    int m = m0 + wr * 64 + mf * 16 + g * 4 + reg;
                    int bi = m >> 11, s = m & 2047;
                    __bf16 o = (__bf16)(acc[mf][nf][reg] + bb);
                    if (mode == 0)
                        Qb[((size_t)(bi * NH + hh) * S_LEN + s) * HD + dd] = o;
                    else
                        Kb[((size_t)(bi * NKV + hh) * S_LEN + s) * HD + dd] = o;
                }
        }
    }
}

// ---------- sliding-window flash attention (no-max softmax, transposed PV) ----------
// grid (32, 16, 2); block 256 = 4 waves; wave = 16 query rows; key tiles of 64
__global__ __launch_bounds__(256) void attn_kernel(const __bf16* __restrict__ Qb,
                                                   const __bf16* __restrict__ Kb,
                                                   const __bf16* __restrict__ Vt,
                                                   __bf16* __restrict__ ctx) {
    __shared__ __align__(16) __bf16 Plds[4][16 * 72];   // per-wave P [q=16][key=64 pad 72]
    __shared__ float lds_l[4][16];
    const int tid = threadIdx.x;
    const int lane = tid & 63, w = tid >> 6;
    const int r = lane & 15, g = lane >> 4;
    const int q0 = blockIdx.x * 64;
    const int h = blockIdx.y, b = blockIdx.z;
    const int kvh = h >> 2;
    const __bf16* Qw = Qb + ((size_t)(b * NH + h) * S_LEN + q0 + w * 16) * HD;
    const __bf16* Kh = Kb + (size_t)(b * NKV + kvh) * S_LEN * HD;
    const __bf16* Vh = Vt + (size_t)(b * NKV + kvh) * HD * S_LEN;
    __bf16* Pw = &Plds[w][0];

    bf16x8 qf[2];
#pragma unroll
    for (int kk = 0; kk < 2; ++kk)
        qf[kk] = *(const bf16x8*)(Qw + r * 64 + kk * 32 + g * 8);

    f32x4 z = {0.f, 0.f, 0.f, 0.f};
    f32x4 o[4];
#pragma unroll
    for (int i = 0; i < 4; ++i) o[i] = z;
    float psum[4] = {0.f, 0.f, 0.f, 0.f};

    const float SC = 0.18033688011112042f;   // D^-0.5 * log2(e)
    const int iqb = q0 + w * 16 + g * 4;     // q index of reg 0

    auto do_tile = [&](int kbase, bool masked) {
        // QK^T: sa[nf] row = q-local (g*4+reg), col = key-local (nf*16+r)
        f32x4 sa[4];
#pragma unroll
        for (int nf = 0; nf < 4; ++nf) sa[nf] = z;
#pragma unroll
        for (int nf = 0; nf < 4; ++nf)
#pragma unroll
            for (int kk = 0; kk < 2; ++kk) {
                bf16x8 kf = *(const bf16x8*)(Kh + (size_t)(kbase + nf * 16 + r) * HD + kk * 32 + g * 8);
                sa[nf] = __builtin_amdgcn_mfma_f32_16x16x32_bf16(qf[kk], kf, sa[nf], 0, 0, 0);
            }
        // exp (no max subtraction); masked only on edge tiles
#pragma unroll
        for (int nf = 0; nf < 4; ++nf) {
            int j = kbase + nf * 16 + r;
#pragma unroll
            for (int reg = 0; reg < 4; ++reg) {
                float x = sa[nf][reg] * SC;
                if (masked) {
                    uint32_t d = (uint32_t)(iqb + reg - j);   // valid iff 0 <= iq-j <= WIN
                    x = (d <= (uint32_t)WIN) ? x : -1e30f;    // exp2(-huge) = 0
                }
                float e = fast_exp2(x);
                psum[reg] += e;
                Pw[(g * 4 + reg) * 72 + nf * 16 + r] = (__bf16)e;
            }
        }
        // PV^T: out^T[d][q] = sum_k Vt[d][k] * P^T[k][q]
#pragma unroll
        for (int kk2 = 0; kk2 < 2; ++kk2) {
            bf16x8 pa = *(const bf16x8*)(Pw + r * 72 + kk2 * 32 + g * 8);   // B-operand: P^T
#pragma unroll
            for (int nf2 = 0; nf2 < 4; ++nf2) {
                bf16x8 vb = *(const bf16x8*)(Vh + (size_t)(nf2 * 16 + r) * S_LEN + kbase + kk2 * 32 + g * 8);
                o[nf2] = __builtin_amdgcn_mfma_f32_16x16x32_bf16(vb, pa, o[nf2], 0, 0, 0);
            }
        }
    };

    if (q0 >= 256) {
        do_tile(q0 - 256, true);    // left ramp
        do_tile(q0 - 192, false);
        do_tile(q0 - 128, false);
        do_tile(q0 - 64,  false);
        do_tile(q0,       true);    // diagonal
    } else {
        for (int kb = 0; kb < q0; kb += 64) do_tile(kb, false);
        do_tile(q0, true);
    }

    // single final row-sum reduce across r (key dim), then exchange via LDS
#pragma unroll
    for (int off = 1; off < 16; off <<= 1)
#pragma unroll
        for (int reg = 0; reg < 4; ++reg)
            psum[reg] += __shfl_xor(psum[reg], off, 64);
    if (r == 0) {
#pragma unroll
        for (int reg = 0; reg < 4; ++reg) lds_l[w][g * 4 + reg] = psum[reg];
    }
    __syncthreads();
    float linv = 1.0f / lds_l[w][r];   // l for q-row r (= output column of this lane)

    // out^T: col = q-local = r, row = d-local = g*4+reg -> consecutive d per reg: 8B stores
    int s = q0 + w * 16 + r;
#pragma unroll
    for (int nf2 = 0; nf2 < 4; ++nf2) {
        bf16x4 pk;
#pragma unroll
        for (int reg = 0; reg < 4; ++reg) pk[reg] = (__bf16)(o[nf2][reg] * linv);
        *reinterpret_cast<bf16x4*>(ctx + ((size_t)(b * S_LEN + s)) * EMB + h * 64 + nf2 * 16 + g * 4) = pk;
    }
}

// ---------- output projection ----------
__global__ __launch_bounds__(256) void gemm_out_kernel(const __bf16* __restrict__ ctxb,
                                                       const __bf16* __restrict__ wot,
                                                       const float* __restrict__ bo,
                                                       float* __restrict__ out) {
    __shared__ __align__(16) __bf16 As[128 * 64];
    __shared__ __align__(16) __bf16 Bs[128 * 64];
    int tid = threadIdx.x;
    int n0 = blockIdx.x * 128, m0 = blockIdx.y * 128;

    f32x4 acc[4][4];
    f32x4 z = {0.f, 0.f, 0.f, 0.f};
#pragma unroll
    for (int i = 0; i < 4; ++i)
#pragma unroll
        for (int j = 0; j < 4; ++j) acc[i][j] = z;

    gemm_core(ctxb, wot, EMB, m0, n0, As, Bs, acc, tid);

    const int lane = tid & 63, w = tid >> 6;
    const int wr = w >> 1, wc = w & 1, r = lane & 15, g = lane >> 4;
#pragma unroll
    for (int nf = 0; nf < 4; ++nf) {
        int n = n0 + wc * 64 + nf * 16 + r;
        float bb = bo[n];
#pragma unroll
        for (int mf = 0; mf < 4; ++mf)
#pragma unroll
            for (int reg = 0; reg < 4; ++reg) {
                int m = m0 + wr * 64 + mf * 16 + g * 4 + reg;
                out[(size_t)m * EMB + n] = acc[mf][nf][reg] + bb;
            }
    }
}

// ---------- launch ----------
extern "C" void kernel_launch(void* const* d_in, const int* in_sizes, int n_in,
                              void* d_out, int out_size, void* d_ws, size_t ws_size,
                              hipStream_t stream) {
    const float* x  = (const float*)d_in[0];
    const float* wq = (const float*)d_in[1];
    const float* bq = (const float*)d_in[2];
    const float* wk = (const float*)d_in[3];
    const float* bk = (const float*)d_in[4];
    const float* wv = (const float*)d_in[5];
    const float* bv = (const float*)d_in[6];
    const float* wo = (const float*)d_in[7];
    const float* bo = (const float*)d_in[8];
    float* out = (float*)d_out;

    char* ws = (char*)d_ws;
    __bf16* xb  = (__bf16*)ws;           ws += (size_t)MROWS * EMB * 2;           // 8 MB
    __bf16* wqt = (__bf16*)ws;           ws += (size_t)EMB * EMB * 2;             // 2 MB
    __bf16* wkt = (__bf16*)ws;           ws += (size_t)256 * EMB * 2;             // 0.5 MB
    __bf16* wvt = (__bf16*)ws;           ws += (size_t)256 * EMB * 2;             // 0.5 MB
    __bf16* wot = (__bf16*)ws;           ws += (size_t)EMB * EMB * 2;             // 2 MB
    __bf16* Qb  = (__bf16*)ws;           ws += (size_t)NB * NH * S_LEN * HD * 2;  // 8 MB
    __bf16* Kb  = (__bf16*)ws;           ws += (size_t)NB * NKV * S_LEN * HD * 2; // 2 MB
    __bf16* Vt  = (__bf16*)ws;           ws += (size_t)NB * NKV * S_LEN * HD * 2; // 2 MB
    __bf16* ctx = (__bf16*)ws;           ws += (size_t)MROWS * EMB * 2;           // 8 MB

    cvt_kernel<<<2048, 256, 0, stream>>>(x, (u16*)xb, (MROWS * EMB) / 8);
    transpose_cvt_kernel<<<dim3(32, 32), dim3(32, 8), 0, stream>>>(wq, (u16*)wqt, EMB, EMB);
    transpose_cvt_kernel<<<dim3(8, 32),  dim3(32, 8), 0, stream>>>(wk, (u16*)wkt, EMB, 256);
    transpose_cvt_kernel<<<dim3(8, 32),  dim3(32, 8), 0, stream>>>(wv, (u16*)wvt, EMB, 256);
    transpose_cvt_kernel<<<dim3(32, 32), dim3(32, 8), 0, stream>>>(wo, (u16*)wot, EMB, EMB);

    gemm_qkv_kernel<<<dim3(12, 32), 256, 0, stream>>>(xb, wqt, wkt, wvt, bq, bk, bv, Qb, Kb, Vt);
    attn_kernel<<<dim3(32, 16, 2), 256, 0, stream>>>(Qb, Kb, Vt, ctx);
    gemm_out_kernel<<<dim3(8, 32), 256, 0, stream>>>(ctx, wot, bo, out);
}

// Round 3
// 112.717 us; speedup vs baseline: 1.0463x; 1.0091x over previous
//
#include <hip/hip_runtime.h>
#include <stdint.h>

typedef unsigned short u16;
typedef __attribute__((ext_vector_type(8))) __bf16 bf16x8;
typedef __attribute__((ext_vector_type(4))) __bf16 bf16x4;
typedef __attribute__((ext_vector_type(4))) float f32x4;

#define S_LEN 2048
#define EMB   1024
#define NH    16
#define NKV   4
#define HD    64
#define WIN   256
#define NB    2
#define MROWS (NB * S_LEN)   // 4096
#define PPAD  72             // P LDS row stride (elements); 144B = 16B-aligned rows

// ---------- helpers ----------
__device__ __forceinline__ u16 f2bf(float f) {
    uint32_t u = __float_as_uint(f);
    uint32_t r = (u + 0x7FFFu + ((u >> 16) & 1u)) >> 16;   // RNE
    return (u16)r;
}

__device__ __forceinline__ float fast_exp2(float x) {
#if __has_builtin(__builtin_amdgcn_exp2f)
    return __builtin_amdgcn_exp2f(x);
#else
    float r; asm("v_exp_f32 %0, %1" : "=v"(r) : "v"(x)); return r;
#endif
}

__device__ __forceinline__ void gload16(const void* g, void* l) {
    __builtin_amdgcn_global_load_lds(
        (const __attribute__((address_space(1))) uint32_t*)(uintptr_t)g,
        (__attribute__((address_space(3))) uint32_t*)(uintptr_t)l,
        16, 0, 0);
}

// ---------- conversion kernels ----------
__global__ __launch_bounds__(256) void cvt_kernel(const float* __restrict__ in,
                                                  u16* __restrict__ out, int n8) {
    int i = blockIdx.x * blockDim.x + threadIdx.x;
    if (i >= n8) return;
    const float4* p = (const float4*)in + (size_t)i * 2;
    float4 a = p[0], b = p[1];
    uint4 q;
    q.x = f2bf(a.x) | ((uint32_t)f2bf(a.y) << 16);
    q.y = f2bf(a.z) | ((uint32_t)f2bf(a.w) << 16);
    q.z = f2bf(b.x) | ((uint32_t)f2bf(b.y) << 16);
    q.w = f2bf(b.z) | ((uint32_t)f2bf(b.w) << 16);
    ((uint4*)out)[i] = q;
}

// in [R][C] f32  ->  out [C][R] bf16
__global__ __launch_bounds__(256) void transpose_cvt_kernel(const float* __restrict__ in,
                                                            u16* __restrict__ out,
                                                            int R, int C) {
    __shared__ float t[32][33];
    int c0 = blockIdx.x * 32, r0 = blockIdx.y * 32;
    int tx = threadIdx.x, ty = threadIdx.y;   // (32, 8)
#pragma unroll
    for (int j = 0; j < 32; j += 8)
        t[ty + j][tx] = in[(size_t)(r0 + ty + j) * C + (c0 + tx)];
    __syncthreads();
#pragma unroll
    for (int j = 0; j < 32; j += 8)
        out[(size_t)(c0 + ty + j) * R + (r0 + tx)] = f2bf(t[tx][ty + j]);
}

// ---------- GEMM core ----------
__device__ __forceinline__ void gemm_core(const __bf16* __restrict__ A, const __bf16* __restrict__ Bt,
                                          int K, int m0, int n0r,
                                          __bf16* As, __bf16* Bs, f32x4 (&acc)[4][4], int tid) {
    const int lane = tid & 63, w = tid >> 6;
    const int wr = w >> 1, wc = w & 1;
    const int r = lane & 15, g = lane >> 4;

    for (int k0 = 0; k0 < K; k0 += 64) {
#pragma unroll
        for (int i = 0; i < 4; ++i) {
            int cb = i * 256 + w * 64;        // wave-uniform chunk base
            int chunk = cb + lane;
            int row = chunk >> 3, cc = chunk & 7;
            gload16(A + (size_t)(m0 + row) * K + k0 + cc * 8, As + cb * 8);
            gload16(Bt + (size_t)(n0r + row) * K + k0 + cc * 8, Bs + cb * 8);
        }
        __syncthreads();
        bf16x8 af[4][2], bfr[4][2];
#pragma unroll
        for (int mf = 0; mf < 4; ++mf)
#pragma unroll
            for (int kk = 0; kk < 2; ++kk)
                af[mf][kk] = *(const bf16x8*)(As + (wr * 64 + mf * 16 + r) * 64 + kk * 32 + g * 8);
#pragma unroll
        for (int nf = 0; nf < 4; ++nf)
#pragma unroll
            for (int kk = 0; kk < 2; ++kk)
                bfr[nf][kk] = *(const bf16x8*)(Bs + (wc * 64 + nf * 16 + r) * 64 + kk * 32 + g * 8);
#pragma unroll
        for (int mf = 0; mf < 4; ++mf)
#pragma unroll
            for (int nf = 0; nf < 4; ++nf)
#pragma unroll
                for (int kk = 0; kk < 2; ++kk)
                    acc[mf][nf] = __builtin_amdgcn_mfma_f32_16x16x32_bf16(
                        af[mf][kk], bfr[nf][kk], acc[mf][nf], 0, 0, 0);
        __syncthreads();
    }
}

// ---------- QKV projection ----------
__global__ __launch_bounds__(256) void gemm_qkv_kernel(
    const __bf16* __restrict__ xb, const __bf16* __restrict__ wqt,
    const __bf16* __restrict__ wkt, const __bf16* __restrict__ wvt,
    const float* __restrict__ bq, const float* __restrict__ bk, const float* __restrict__ bv,
    __bf16* __restrict__ Qb, __bf16* __restrict__ Kb, __bf16* __restrict__ Vt) {
    __shared__ __align__(16) __bf16 As[128 * 64];
    __shared__ __align__(16) __bf16 Bs[128 * 64];
    int tid = threadIdx.x;
    int n0 = blockIdx.x * 128, m0 = blockIdx.y * 128;

    const __bf16* Bt; int n0r; const float* bias; int mode;
    if (n0 < 1024)      { Bt = wqt; n0r = n0;        bias = bq; mode = 0; }
    else if (n0 < 1280) { Bt = wkt; n0r = n0 - 1024; bias = bk; mode = 1; }
    else                { Bt = wvt; n0r = n0 - 1280; bias = bv; mode = 2; }

    f32x4 acc[4][4];
    f32x4 z = {0.f, 0.f, 0.f, 0.f};
#pragma unroll
    for (int i = 0; i < 4; ++i)
#pragma unroll
        for (int j = 0; j < 4; ++j) acc[i][j] = z;

    gemm_core(xb, Bt, EMB, m0, n0r, As, Bs, acc, tid);

    const int lane = tid & 63, w = tid >> 6;
    const int wr = w >> 1, wc = w & 1, r = lane & 15, g = lane >> 4;
#pragma unroll
    for (int nf = 0; nf < 4; ++nf) {
        int nn = n0r + wc * 64 + nf * 16 + r;
        float bb = bias[nn];
        int hh = nn >> 6, dd = nn & 63;
        if (mode == 2) {
            // V transposed [D][S]: regs -> consecutive s, pack 4 bf16 = 8B store
#pragma unroll
            for (int mf = 0; mf < 4; ++mf) {
                int s0 = m0 + wr * 64 + mf * 16 + g * 4;
                int bi = s0 >> 11, s = s0 & 2047;
                bf16x4 pk;
#pragma unroll
                for (int reg = 0; reg < 4; ++reg) pk[reg] = (__bf16)(acc[mf][nf][reg] + bb);
                *reinterpret_cast<bf16x4*>(Vt + ((size_t)(bi * NKV + hh) * HD + dd) * S_LEN + s) = pk;
            }
        } else {
#pragma unroll
            for (int mf = 0; mf < 4; ++mf)
#pragma unroll
                for (int reg = 0; reg < 4; ++reg) {
                    int m = m0 + wr * 64 + mf * 16 + g * 4 + reg;
                    int bi = m >> 11, s = m & 2047;
                    __bf16 o = (__bf16)(acc[mf][nf][reg] + bb);
                    if (mode == 0)
                        Qb[((size_t)(bi * NH + hh) * S_LEN + s) * HD + dd] = o;
                    else
                        Kb[((size_t)(bi * NKV + hh) * S_LEN + s) * HD + dd] = o;
                }
        }
    }
}

// ---------- sliding-window flash attention ----------
// Swapped-QK form: sa = mfma(K, Q) -> C[key on g][q on r]; q is lane-constant.
// Register-pipelined: K double-buffered across tiles, V issued at tile start.
// grid (32, 16, 2); block 256 = 4 waves; wave = 16 query rows; key tiles of 64
__global__ __launch_bounds__(256, 3) void attn_kernel(const __bf16* __restrict__ Qb,
                                                      const __bf16* __restrict__ Kb,
                                                      const __bf16* __restrict__ Vt,
                                                      __bf16* __restrict__ ctx) {
    __shared__ __align__(16) __bf16 Plds[4][16 * PPAD];   // per-wave P [q=16][k=64 pad]
    const int tid = threadIdx.x;
    const int lane = tid & 63, w = tid >> 6;
    const int r = lane & 15, g = lane >> 4;
    const int q0 = blockIdx.x * 64;
    const int h = blockIdx.y, b = blockIdx.z;
    const int kvh = h >> 2;
    const __bf16* Qw = Qb + ((size_t)(b * NH + h) * S_LEN + q0 + w * 16) * HD;
    const __bf16* Kh = Kb + (size_t)(b * NKV + kvh) * S_LEN * HD;
    const __bf16* Vh = Vt + (size_t)(b * NKV + kvh) * HD * S_LEN;
    __bf16* Pw = &Plds[w][0];

    // Q fragment (B-operand): B[col=q=r][k = kk*32+g*8+j]
    bf16x8 qf[2];
#pragma unroll
    for (int kk = 0; kk < 2; ++kk)
        qf[kk] = *(const bf16x8*)(Qw + r * 64 + kk * 32 + g * 8);

    f32x4 z = {0.f, 0.f, 0.f, 0.f};
    f32x4 o[4];
#pragma unroll
    for (int i = 0; i < 4; ++i) o[i] = z;
    float psum = 0.f;

    const float SC = 0.18033688011112042f;   // D^-0.5 * log2(e)
    const int iq = q0 + w * 16 + r;          // this lane's query index (lane-constant)

    // K fragment (A-operand): A[row=key=r][k on g]
    auto loadK = [&](bf16x8 (&kf)[4][2], int kbase) {
#pragma unroll
        for (int nf = 0; nf < 4; ++nf)
#pragma unroll
            for (int kk = 0; kk < 2; ++kk)
                kf[nf][kk] = *(const bf16x8*)(Kh + (size_t)(kbase + nf * 16 + r) * HD + kk * 32 + g * 8);
    };
    // V^T fragment (A-operand of PV): A[row=d=r][k on g]
    auto loadV = [&](bf16x8 (&vf)[4][2], int kbase) {
#pragma unroll
        for (int nf = 0; nf < 4; ++nf)
#pragma unroll
            for (int kk = 0; kk < 2; ++kk)
                vf[nf][kk] = *(const bf16x8*)(Vh + (size_t)(nf * 16 + r) * S_LEN + kbase + kk * 32 + g * 8);
    };

    auto tile = [&](bf16x8 (&kf)[4][2], bf16x8 (&vf)[4][2], int kbase, bool masked) {
        // QK^T swapped: sa[nf][reg] = S[key = kbase + nf*16 + g*4 + reg][q = r]
        f32x4 sa[4];
#pragma unroll
        for (int nf = 0; nf < 4; ++nf) sa[nf] = z;
#pragma unroll
        for (int nf = 0; nf < 4; ++nf)
#pragma unroll
            for (int kk = 0; kk < 2; ++kk)
                sa[nf] = __builtin_amdgcn_mfma_f32_16x16x32_bf16(kf[nf][kk], qf[kk], sa[nf], 0, 0, 0);
        // exp; P[q=r][k] write: 4 consecutive k per (nf) -> b64 packed
#pragma unroll
        for (int nf = 0; nf < 4; ++nf) {
            int jb = kbase + nf * 16 + g * 4;
            bf16x4 pk;
#pragma unroll
            for (int reg = 0; reg < 4; ++reg) {
                float x = sa[nf][reg] * SC;
                if (masked) {
                    uint32_t d = (uint32_t)(iq - (jb + reg));   // valid iff 0 <= iq-j <= WIN
                    x = (d <= (uint32_t)WIN) ? x : -1e30f;
                }
                float e = fast_exp2(x);
                psum += e;
                pk[reg] = (__bf16)e;
            }
            *reinterpret_cast<bf16x4*>(Pw + r * PPAD + nf * 16 + g * 4) = pk;
        }
        // PV: o[nf2] = mfma(V^T frag, P frag); B[col=q=r][k on g] read from P row r
#pragma unroll
        for (int kk2 = 0; kk2 < 2; ++kk2) {
            bf16x8 pa = *(const bf16x8*)(Pw + r * PPAD + kk2 * 32 + g * 8);
#pragma unroll
            for (int nf2 = 0; nf2 < 4; ++nf2)
                o[nf2] = __builtin_amdgcn_mfma_f32_16x16x32_bf16(vf[nf2][kk2], pa, o[nf2], 0, 0, 0);
        }
    };

    if (q0 >= 256) {
        bf16x8 kfa[4][2], kfb[4][2], vfa[4][2];
        loadK(kfa, q0 - 256);
        loadV(vfa, q0 - 256); loadK(kfb, q0 - 192);
        tile(kfa, vfa, q0 - 256, true);
        loadV(vfa, q0 - 192); loadK(kfa, q0 - 128);
        tile(kfb, vfa, q0 - 192, false);
        loadV(vfa, q0 - 128); loadK(kfb, q0 - 64);
        tile(kfa, vfa, q0 - 128, false);
        loadV(vfa, q0 - 64);  loadK(kfa, q0);
        tile(kfb, vfa, q0 - 64, false);
        loadV(vfa, q0);
        tile(kfa, vfa, q0, true);
    } else {
        bf16x8 kfa[4][2], vfa[4][2];
        for (int kb2 = 0; kb2 <= q0; kb2 += 64) {
            loadK(kfa, kb2); loadV(vfa, kb2);
            tile(kfa, vfa, kb2, kb2 == q0);   // only diagonal tile needs mask when q0 < 256
        }
    }

    // row-sum: reduce over the 4 g-groups (q = r is lane-constant)
    psum += __shfl_xor(psum, 16, 64);
    psum += __shfl_xor(psum, 32, 64);
    float linv = 1.0f / psum;

    // o[nf2][reg] = out[d = nf2*16 + g*4 + reg][q = r]; 4 consecutive d -> 8B store
    int s = q0 + w * 16 + r;
#pragma unroll
    for (int nf2 = 0; nf2 < 4; ++nf2) {
        bf16x4 pk;
#pragma unroll
        for (int reg = 0; reg < 4; ++reg) pk[reg] = (__bf16)(o[nf2][reg] * linv);
        *reinterpret_cast<bf16x4*>(ctx + ((size_t)(b * S_LEN + s)) * EMB + h * 64 + nf2 * 16 + g * 4) = pk;
    }
}

// ---------- output projection ----------
__global__ __launch_bounds__(256) void gemm_out_kernel(const __bf16* __restrict__ ctxb,
                                                       const __bf16* __restrict__ wot,
                                                       const float* __restrict__ bo,
                                                       float* __restrict__ out) {
    __shared__ __align__(16) __bf16 As[128 * 64];
    __shared__ __align__(16) __bf16 Bs[128 * 64];
    int tid = threadIdx.x;
    int n0 = blockIdx.x * 128, m0 = blockIdx.y * 128;

    f32x4 acc[4][4];
    f32x4 z = {0.f, 0.f, 0.f, 0.f};
#pragma unroll
    for (int i = 0; i < 4; ++i)
#pragma unroll
        for (int j = 0; j < 4; ++j) acc[i][j] = z;

    gemm_core(ctxb, wot, EMB, m0, n0, As, Bs, acc, tid);

    const int lane = tid & 63, w = tid >> 6;
    const int wr = w >> 1, wc = w & 1, r = lane & 15, g = lane >> 4;
#pragma unroll
    for (int nf = 0; nf < 4; ++nf) {
        int n = n0 + wc * 64 + nf * 16 + r;
        float bb = bo[n];
#pragma unroll
        for (int mf = 0; mf < 4; ++mf)
#pragma unroll
            for (int reg = 0; reg < 4; ++reg) {
                int m = m0 + wr * 64 + mf * 16 + g * 4 + reg;
                out[(size_t)m * EMB + n] = acc[mf][nf][reg] + bb;
            }
    }
}

// ---------- launch ----------
extern "C" void kernel_launch(void* const* d_in, const int* in_sizes, int n_in,
                              void* d_out, int out_size, void* d_ws, size_t ws_size,
                              hipStream_t stream) {
    const float* x  = (const float*)d_in[0];
    const float* wq = (const float*)d_in[1];
    const float* bq = (const float*)d_in[2];
    const float* wk = (const float*)d_in[3];
    const float* bk = (const float*)d_in[4];
    const float* wv = (const float*)d_in[5];
    const float* bv = (const float*)d_in[6];
    const float* wo = (const float*)d_in[7];
    const float* bo = (const float*)d_in[8];
    float* out = (float*)d_out;

    char* ws = (char*)d_ws;
    __bf16* xb  = (__bf16*)ws;           ws += (size_t)MROWS * EMB * 2;           // 8 MB
    __bf16* wqt = (__bf16*)ws;           ws += (size_t)EMB * EMB * 2;             // 2 MB
    __bf16* wkt = (__bf16*)ws;           ws += (size_t)256 * EMB * 2;             // 0.5 MB
    __bf16* wvt = (__bf16*)ws;           ws += (size_t)256 * EMB * 2;             // 0.5 MB
    __bf16* wot = (__bf16*)ws;           ws += (size_t)EMB * EMB * 2;             // 2 MB
    __bf16* Qb  = (__bf16*)ws;           ws += (size_t)NB * NH * S_LEN * HD * 2;  // 8 MB
    __bf16* Kb  = (__bf16*)ws;           ws += (size_t)NB * NKV * S_LEN * HD * 2; // 2 MB
    __bf16* Vt  = (__bf16*)ws;           ws += (size_t)NB * NKV * S_LEN * HD * 2; // 2 MB
    __bf16* ctx = (__bf16*)ws;           ws += (size_t)MROWS * EMB * 2;           // 8 MB

    cvt_kernel<<<2048, 256, 0, stream>>>(x, (u16*)xb, (MROWS * EMB) / 8);
    transpose_cvt_kernel<<<dim3(32, 32), dim3(32, 8), 0, stream>>>(wq, (u16*)wqt, EMB, EMB);
    transpose_cvt_kernel<<<dim3(8, 32),  dim3(32, 8), 0, stream>>>(wk, (u16*)wkt, EMB, 256);
    transpose_cvt_kernel<<<dim3(8, 32),  dim3(32, 8), 0, stream>>>(wv, (u16*)wvt, EMB, 256);
    transpose_cvt_kernel<<<dim3(32, 32), dim3(32, 8), 0, stream>>>(wo, (u16*)wot, EMB, EMB);

    gemm_qkv_kernel<<<dim3(12, 32), 256, 0, stream>>>(xb, wqt, wkt, wvt, bq, bk, bv, Qb, Kb, Vt);
    attn_kernel<<<dim3(32, 16, 2), 256, 0, stream>>>(Qb, Kb, Vt, ctx);
    gemm_out_kernel<<<dim3(8, 32), 256, 0, stream>>>(ctx, wot, bo, out);
}

// Round 4
// 112.632 us; speedup vs baseline: 1.0471x; 1.0008x over previous
//
#include <hip/hip_runtime.h>
#include <stdint.h>

typedef unsigned short u16;
typedef __attribute__((ext_vector_type(8))) __bf16 bf16x8;
typedef __attribute__((ext_vector_type(4))) __bf16 bf16x4;
typedef __attribute__((ext_vector_type(4))) float f32x4;

#define S_LEN 2048
#define EMB   1024
#define NH    16
#define NKV   4
#define HD    64
#define WIN   256
#define NB    2
#define MROWS (NB * S_LEN)   // 4096
#define PPAD  72             // P LDS row stride (elements); 144B rows, 16B-aligned

// ---------- helpers ----------
__device__ __forceinline__ u16 f2bf(float f) {
    uint32_t u = __float_as_uint(f);
    uint32_t r = (u + 0x7FFFu + ((u >> 16) & 1u)) >> 16;   // RNE
    return (u16)r;
}

__device__ __forceinline__ float fast_exp2(float x) {
#if __has_builtin(__builtin_amdgcn_exp2f)
    return __builtin_amdgcn_exp2f(x);
#else
    float r; asm("v_exp_f32 %0, %1" : "=v"(r) : "v"(x)); return r;
#endif
}

__device__ __forceinline__ void gload16(const void* g, void* l) {
    __builtin_amdgcn_global_load_lds(
        (const __attribute__((address_space(1))) uint32_t*)(uintptr_t)g,
        (__attribute__((address_space(3))) uint32_t*)(uintptr_t)l,
        16, 0, 0);
}

// ---------- conversion kernels ----------
__global__ __launch_bounds__(256) void cvt_kernel(const float* __restrict__ in,
                                                  u16* __restrict__ out, int n8) {
    int i = blockIdx.x * blockDim.x + threadIdx.x;
    if (i >= n8) return;
    const float4* p = (const float4*)in + (size_t)i * 2;
    float4 a = p[0], b = p[1];
    uint4 q;
    q.x = f2bf(a.x) | ((uint32_t)f2bf(a.y) << 16);
    q.y = f2bf(a.z) | ((uint32_t)f2bf(a.w) << 16);
    q.z = f2bf(b.x) | ((uint32_t)f2bf(b.y) << 16);
    q.w = f2bf(b.z) | ((uint32_t)f2bf(b.w) << 16);
    ((uint4*)out)[i] = q;
}

// in [R][C] f32  ->  out [C][R] bf16
__global__ __launch_bounds__(256) void transpose_cvt_kernel(const float* __restrict__ in,
                                                            u16* __restrict__ out,
                                                            int R, int C) {
    __shared__ float t[32][33];
    int c0 = blockIdx.x * 32, r0 = blockIdx.y * 32;
    int tx = threadIdx.x, ty = threadIdx.y;   // (32, 8)
#pragma unroll
    for (int j = 0; j < 32; j += 8)
        t[ty + j][tx] = in[(size_t)(r0 + ty + j) * C + (c0 + tx)];
    __syncthreads();
#pragma unroll
    for (int j = 0; j < 32; j += 8)
        out[(size_t)(c0 + ty + j) * R + (r0 + tx)] = f2bf(t[tx][ty + j]);
}

// ---------- GEMM core ----------
__device__ __forceinline__ void gemm_core(const __bf16* __restrict__ A, const __bf16* __restrict__ Bt,
                                          int K, int m0, int n0r,
                                          __bf16* As, __bf16* Bs, f32x4 (&acc)[4][4], int tid) {
    const int lane = tid & 63, w = tid >> 6;
    const int wr = w >> 1, wc = w & 1;
    const int r = lane & 15, g = lane >> 4;

    for (int k0 = 0; k0 < K; k0 += 64) {
#pragma unroll
        for (int i = 0; i < 4; ++i) {
            int cb = i * 256 + w * 64;        // wave-uniform chunk base
            int chunk = cb + lane;
            int row = chunk >> 3, cc = chunk & 7;
            gload16(A + (size_t)(m0 + row) * K + k0 + cc * 8, As + cb * 8);
            gload16(Bt + (size_t)(n0r + row) * K + k0 + cc * 8, Bs + cb * 8);
        }
        __syncthreads();
        bf16x8 af[4][2], bfr[4][2];
#pragma unroll
        for (int mf = 0; mf < 4; ++mf)
#pragma unroll
            for (int kk = 0; kk < 2; ++kk)
                af[mf][kk] = *(const bf16x8*)(As + (wr * 64 + mf * 16 + r) * 64 + kk * 32 + g * 8);
#pragma unroll
        for (int nf = 0; nf < 4; ++nf)
#pragma unroll
            for (int kk = 0; kk < 2; ++kk)
                bfr[nf][kk] = *(const bf16x8*)(Bs + (wc * 64 + nf * 16 + r) * 64 + kk * 32 + g * 8);
#pragma unroll
        for (int mf = 0; mf < 4; ++mf)
#pragma unroll
            for (int nf = 0; nf < 4; ++nf)
#pragma unroll
                for (int kk = 0; kk < 2; ++kk)
                    acc[mf][nf] = __builtin_amdgcn_mfma_f32_16x16x32_bf16(
                        af[mf][kk], bfr[nf][kk], acc[mf][nf], 0, 0, 0);
        __syncthreads();
    }
}

// ---------- QKV projection ----------
__global__ __launch_bounds__(256) void gemm_qkv_kernel(
    const __bf16* __restrict__ xb, const __bf16* __restrict__ wqt,
    const __bf16* __restrict__ wkt, const __bf16* __restrict__ wvt,
    const float* __restrict__ bq, const float* __restrict__ bk, const float* __restrict__ bv,
    __bf16* __restrict__ Qb, __bf16* __restrict__ Kb, __bf16* __restrict__ Vt) {
    __shared__ __align__(16) __bf16 As[128 * 64];
    __shared__ __align__(16) __bf16 Bs[128 * 64];
    int tid = threadIdx.x;
    int n0 = blockIdx.x * 128, m0 = blockIdx.y * 128;

    const __bf16* Bt; int n0r; const float* bias; int mode;
    if (n0 < 1024)      { Bt = wqt; n0r = n0;        bias = bq; mode = 0; }
    else if (n0 < 1280) { Bt = wkt; n0r = n0 - 1024; bias = bk; mode = 1; }
    else                { Bt = wvt; n0r = n0 - 1280; bias = bv; mode = 2; }

    f32x4 acc[4][4];
    f32x4 z = {0.f, 0.f, 0.f, 0.f};
#pragma unroll
    for (int i = 0; i < 4; ++i)
#pragma unroll
        for (int j = 0; j < 4; ++j) acc[i][j] = z;

    gemm_core(xb, Bt, EMB, m0, n0r, As, Bs, acc, tid);

    const int lane = tid & 63, w = tid >> 6;
    const int wr = w >> 1, wc = w & 1, r = lane & 15, g = lane >> 4;
#pragma unroll
    for (int nf = 0; nf < 4; ++nf) {
        int nn = n0r + wc * 64 + nf * 16 + r;
        float bb = bias[nn];
        int hh = nn >> 6, dd = nn & 63;
        if (mode == 2) {
            // V transposed [D][S]: regs -> consecutive s, pack 4 bf16 = 8B store
#pragma unroll
            for (int mf = 0; mf < 4; ++mf) {
                int s0 = m0 + wr * 64 + mf * 16 + g * 4;
                int bi = s0 >> 11, s = s0 & 2047;
                bf16x4 pk;
#pragma unroll
                for (int reg = 0; reg < 4; ++reg) pk[reg] = (__bf16)(acc[mf][nf][reg] + bb);
                *reinterpret_cast<bf16x4*>(Vt + ((size_t)(bi * NKV + hh) * HD + dd) * S_LEN + s) = pk;
            }
        } else {
#pragma unroll
            for (int mf = 0; mf < 4; ++mf)
#pragma unroll
                for (int reg = 0; reg < 4; ++reg) {
                    int m = m0 + wr * 64 + mf * 16 + g * 4 + reg;
                    int bi = m >> 11, s = m & 2047;
                    __bf16 o = (__bf16)(acc[mf][nf][reg] + bb);
                    if (mode == 0)
                        Qb[((size_t)(bi * NH + hh) * S_LEN + s) * HD + dd] = o;
                    else
                        Kb[((size_t)(bi * NKV + hh) * S_LEN + s) * HD + dd] = o;
                }
        }
    }
}

// ---------- sliding-window flash attention ----------
// Swapped-QK, register-pipelined with sched_barrier(0) walls forcing issue order:
//   {issue V(t), K(t+1)} | WALL | {QK(t), exp, P->LDS, PV(t)} | WALL | ...
// grid (32, 16, 2); block 256 = 4 waves; wave = 16 query rows; key tiles of 64
__global__ __launch_bounds__(256, 3) void attn_kernel(const __bf16* __restrict__ Qb,
                                                      const __bf16* __restrict__ Kb,
                                                      const __bf16* __restrict__ Vt,
                                                      __bf16* __restrict__ ctx) {
    __shared__ __align__(16) __bf16 Plds[4][16 * PPAD];   // per-wave P [q=16][k=64 pad]
    const int tid = threadIdx.x;
    const int lane = tid & 63, w = tid >> 6;
    const int r = lane & 15, g = lane >> 4;
    const int q0 = blockIdx.x * 64;
    const int h = blockIdx.y, b = blockIdx.z;
    const int kvh = h >> 2;
    const __bf16* Qw = Qb + ((size_t)(b * NH + h) * S_LEN + q0 + w * 16) * HD;
    const __bf16* Kh = Kb + (size_t)(b * NKV + kvh) * S_LEN * HD;
    const __bf16* Vh = Vt + (size_t)(b * NKV + kvh) * HD * S_LEN;
    __bf16* Pw = &Plds[w][0];

    // Q fragment (B-operand): B[col=q=r][k = kk*32+g*8+j]
    bf16x8 qf[2];
#pragma unroll
    for (int kk = 0; kk < 2; ++kk)
        qf[kk] = *(const bf16x8*)(Qw + r * 64 + kk * 32 + g * 8);

    f32x4 z = {0.f, 0.f, 0.f, 0.f};
    f32x4 o[4];
#pragma unroll
    for (int i = 0; i < 4; ++i) o[i] = z;
    float psum = 0.f;

    const float SC = 0.18033688011112042f;   // D^-0.5 * log2(e)
    const int iq = q0 + w * 16 + r;          // this lane's query index (lane-constant)

    // K fragment (A-operand): A[row=key=r][k on g]
    auto loadK = [&](bf16x8 (&kf)[4][2], int kbase) {
#pragma unroll
        for (int nf = 0; nf < 4; ++nf)
#pragma unroll
            for (int kk = 0; kk < 2; ++kk)
                kf[nf][kk] = *(const bf16x8*)(Kh + (size_t)(kbase + nf * 16 + r) * HD + kk * 32 + g * 8);
    };
    // V^T fragment (A-operand of PV): A[row=d=r][k on g]
    auto loadV = [&](bf16x8 (&vf)[4][2], int kbase) {
#pragma unroll
        for (int nf = 0; nf < 4; ++nf)
#pragma unroll
            for (int kk = 0; kk < 2; ++kk)
                vf[nf][kk] = *(const bf16x8*)(Vh + (size_t)(nf * 16 + r) * S_LEN + kbase + kk * 32 + g * 8);
    };

    auto tile = [&](bf16x8 (&kf)[4][2], bf16x8 (&vf)[4][2], int kbase, bool masked) {
        // QK^T swapped: sa[nf][reg] = S[key = kbase + nf*16 + g*4 + reg][q = r]
        f32x4 sa[4];
#pragma unroll
        for (int nf = 0; nf < 4; ++nf) sa[nf] = z;
#pragma unroll
        for (int nf = 0; nf < 4; ++nf)
#pragma unroll
            for (int kk = 0; kk < 2; ++kk)
                sa[nf] = __builtin_amdgcn_mfma_f32_16x16x32_bf16(kf[nf][kk], qf[kk], sa[nf], 0, 0, 0);
        // exp; P[q=r][k] write: 4 consecutive k per (nf) -> b64 packed
#pragma unroll
        for (int nf = 0; nf < 4; ++nf) {
            int jb = kbase + nf * 16 + g * 4;
            bf16x4 pk;
#pragma unroll
            for (int reg = 0; reg < 4; ++reg) {
                float x = sa[nf][reg] * SC;
                if (masked) {
                    uint32_t d = (uint32_t)(iq - (jb + reg));   // valid iff 0 <= iq-j <= WIN
                    x = (d <= (uint32_t)WIN) ? x : -1e30f;
                }
                float e = fast_exp2(x);
                psum += e;
                pk[reg] = (__bf16)e;
            }
            *reinterpret_cast<bf16x4*>(Pw + r * PPAD + nf * 16 + g * 4) = pk;
        }
        // PV: o[nf2] = mfma(V^T frag, P frag); B[col=q=r][k on g] read from P row r
#pragma unroll
        for (int kk2 = 0; kk2 < 2; ++kk2) {
            bf16x8 pa = *(const bf16x8*)(Pw + r * PPAD + kk2 * 32 + g * 8);
#pragma unroll
            for (int nf2 = 0; nf2 < 4; ++nf2)
                o[nf2] = __builtin_amdgcn_mfma_f32_16x16x32_bf16(vf[nf2][kk2], pa, o[nf2], 0, 0, 0);
        }
    };

    if (q0 >= 256) {
        bf16x8 kcur[4][2], knxt[4][2], vf[4][2];
        loadK(kcur, q0 - 256);
        __builtin_amdgcn_sched_barrier(0);
        // t=0
        loadV(vf, q0 - 256);
        loadK(knxt, q0 - 192);
        __builtin_amdgcn_sched_barrier(0);
        tile(kcur, vf, q0 - 256, true);
        __builtin_amdgcn_sched_barrier(0);
        // t=1
        loadV(vf, q0 - 192);
        loadK(kcur, q0 - 128);
        __builtin_amdgcn_sched_barrier(0);
        tile(knxt, vf, q0 - 192, false);
        __builtin_amdgcn_sched_barrier(0);
        // t=2
        loadV(vf, q0 - 128);
        loadK(knxt, q0 - 64);
        __builtin_amdgcn_sched_barrier(0);
        tile(kcur, vf, q0 - 128, false);
        __builtin_amdgcn_sched_barrier(0);
        // t=3
        loadV(vf, q0 - 64);
        loadK(kcur, q0);
        __builtin_amdgcn_sched_barrier(0);
        tile(knxt, vf, q0 - 64, false);
        __builtin_amdgcn_sched_barrier(0);
        // t=4
        loadV(vf, q0);
        __builtin_amdgcn_sched_barrier(0);
        tile(kcur, vf, q0, true);
    } else {
        bf16x8 kfa[4][2], vfa[4][2];
        for (int kb2 = 0; kb2 <= q0; kb2 += 64) {
            loadK(kfa, kb2); loadV(vfa, kb2);
            tile(kfa, vfa, kb2, kb2 == q0);   // only diagonal tile needs mask when q0 < 256
        }
    }

    // row-sum: reduce over the 4 g-groups (q = r is lane-constant)
    psum += __shfl_xor(psum, 16, 64);
    psum += __shfl_xor(psum, 32, 64);
    float linv = 1.0f / psum;

    // o[nf2][reg] = out[d = nf2*16 + g*4 + reg][q = r]; 4 consecutive d -> 8B store
    int s = q0 + w * 16 + r;
#pragma unroll
    for (int nf2 = 0; nf2 < 4; ++nf2) {
        bf16x4 pk;
#pragma unroll
        for (int reg = 0; reg < 4; ++reg) pk[reg] = (__bf16)(o[nf2][reg] * linv);
        *reinterpret_cast<bf16x4*>(ctx + ((size_t)(b * S_LEN + s)) * EMB + h * 64 + nf2 * 16 + g * 4) = pk;
    }
}

// ---------- output projection ----------
__global__ __launch_bounds__(256) void gemm_out_kernel(const __bf16* __restrict__ ctxb,
                                                       const __bf16* __restrict__ wot,
                                                       const float* __restrict__ bo,
                                                       float* __restrict__ out) {
    __shared__ __align__(16) __bf16 As[128 * 64];
    __shared__ __align__(16) __bf16 Bs[128 * 64];
    int tid = threadIdx.x;
    int n0 = blockIdx.x * 128, m0 = blockIdx.y * 128;

    f32x4 acc[4][4];
    f32x4 z = {0.f, 0.f, 0.f, 0.f};
#pragma unroll
    for (int i = 0; i < 4; ++i)
#pragma unroll
        for (int j = 0; j < 4; ++j) acc[i][j] = z;

    gemm_core(ctxb, wot, EMB, m0, n0, As, Bs, acc, tid);

    const int lane = tid & 63, w = tid >> 6;
    const int wr = w >> 1, wc = w & 1, r = lane & 15, g = lane >> 4;
#pragma unroll
    for (int nf = 0; nf < 4; ++nf) {
        int n = n0 + wc * 64 + nf * 16 + r;
        float bb = bo[n];
#pragma unroll
        for (int mf = 0; mf < 4; ++mf)
#pragma unroll
            for (int reg = 0; reg < 4; ++reg) {
                int m = m0 + wr * 64 + mf * 16 + g * 4 + reg;
                out[(size_t)m * EMB + n] = acc[mf][nf][reg] + bb;
            }
    }
}

// ---------- launch ----------
extern "C" void kernel_launch(void* const* d_in, const int* in_sizes, int n_in,
                              void* d_out, int out_size, void* d_ws, size_t ws_size,
                              hipStream_t stream) {
    const float* x  = (const float*)d_in[0];
    const float* wq = (const float*)d_in[1];
    const float* bq = (const float*)d_in[2];
    const float* wk = (const float*)d_in[3];
    const float* bk = (const float*)d_in[4];
    const float* wv = (const float*)d_in[5];
    const float* bv = (const float*)d_in[6];
    const float* wo = (const float*)d_in[7];
    const float* bo = (const float*)d_in[8];
    float* out = (float*)d_out;

    char* ws = (char*)d_ws;
    __bf16* xb  = (__bf16*)ws;           ws += (size_t)MROWS * EMB * 2;           // 8 MB
    __bf16* wqt = (__bf16*)ws;           ws += (size_t)EMB * EMB * 2;             // 2 MB
    __bf16* wkt = (__bf16*)ws;           ws += (size_t)256 * EMB * 2;             // 0.5 MB
    __bf16* wvt = (__bf16*)ws;           ws += (size_t)256 * EMB * 2;             // 0.5 MB
    __bf16* wot = (__bf16*)ws;           ws += (size_t)EMB * EMB * 2;             // 2 MB
    __bf16* Qb  = (__bf16*)ws;           ws += (size_t)NB * NH * S_LEN * HD * 2;  // 8 MB
    __bf16* Kb  = (__bf16*)ws;           ws += (size_t)NB * NKV * S_LEN * HD * 2; // 2 MB
    __bf16* Vt  = (__bf16*)ws;           ws += (size_t)NB * NKV * S_LEN * HD * 2; // 2 MB
    __bf16* ctx = (__bf16*)ws;           ws += (size_t)MROWS * EMB * 2;           // 8 MB

    cvt_kernel<<<2048, 256, 0, stream>>>(x, (u16*)xb, (MROWS * EMB) / 8);
    transpose_cvt_kernel<<<dim3(32, 32), dim3(32, 8), 0, stream>>>(wq, (u16*)wqt, EMB, EMB);
    transpose_cvt_kernel<<<dim3(8, 32),  dim3(32, 8), 0, stream>>>(wk, (u16*)wkt, EMB, 256);
    transpose_cvt_kernel<<<dim3(8, 32),  dim3(32, 8), 0, stream>>>(wv, (u16*)wvt, EMB, 256);
    transpose_cvt_kernel<<<dim3(32, 32), dim3(32, 8), 0, stream>>>(wo, (u16*)wot, EMB, EMB);

    gemm_qkv_kernel<<<dim3(12, 32), 256, 0, stream>>>(xb, wqt, wkt, wvt, bq, bk, bv, Qb, Kb, Vt);
    attn_kernel<<<dim3(32, 16, 2), 256, 0, stream>>>(Qb, Kb, Vt, ctx);
    gemm_out_kernel<<<dim3(8, 32), 256, 0, stream>>>(ctx, wot, bo, out);
}

// Round 5
// 88.060 us; speedup vs baseline: 1.3393x; 1.2790x over previous
//
#include <hip/hip_runtime.h>
#include <stdint.h>

typedef unsigned short u16;
typedef __attribute__((ext_vector_type(8))) __bf16 bf16x8;
typedef __attribute__((ext_vector_type(4))) __bf16 bf16x4;
typedef __attribute__((ext_vector_type(4))) float f32x4;

#define S_LEN 2048
#define EMB   1024
#define NH    16
#define NKV   4
#define HD    64
#define WIN   256
#define NB    2
#define MROWS (NB * S_LEN)   // 4096
#define PPAD  72             // P LDS row stride (elements)

// ---------- helpers ----------
__device__ __forceinline__ u16 f2bf(float f) {
    uint32_t u = __float_as_uint(f);
    uint32_t r = (u + 0x7FFFu + ((u >> 16) & 1u)) >> 16;   // RNE
    return (u16)r;
}

__device__ __forceinline__ float fast_exp2(float x) {
#if __has_builtin(__builtin_amdgcn_exp2f)
    return __builtin_amdgcn_exp2f(x);
#else
    float r; asm("v_exp_f32 %0, %1" : "=v"(r) : "v"(x)); return r;
#endif
}

__device__ __forceinline__ void gload16(const void* g, void* l) {
    __builtin_amdgcn_global_load_lds(
        (const __attribute__((address_space(1))) uint32_t*)(uintptr_t)g,
        (__attribute__((address_space(3))) uint32_t*)(uintptr_t)l,
        16, 0, 0);
}

// ---------- conversion kernels ----------
__global__ __launch_bounds__(256) void cvt_kernel(const float* __restrict__ in,
                                                  u16* __restrict__ out, int n8) {
    int i = blockIdx.x * blockDim.x + threadIdx.x;
    if (i >= n8) return;
    const float4* p = (const float4*)in + (size_t)i * 2;
    float4 a = p[0], b = p[1];
    uint4 q;
    q.x = f2bf(a.x) | ((uint32_t)f2bf(a.y) << 16);
    q.y = f2bf(a.z) | ((uint32_t)f2bf(a.w) << 16);
    q.z = f2bf(b.x) | ((uint32_t)f2bf(b.y) << 16);
    q.w = f2bf(b.z) | ((uint32_t)f2bf(b.w) << 16);
    ((uint4*)out)[i] = q;
}

// in [R][C] f32  ->  out [C][R] bf16
__global__ __launch_bounds__(256) void transpose_cvt_kernel(const float* __restrict__ in,
                                                            u16* __restrict__ out,
                                                            int R, int C) {
    __shared__ float t[32][33];
    int c0 = blockIdx.x * 32, r0 = blockIdx.y * 32;
    int tx = threadIdx.x, ty = threadIdx.y;   // (32, 8)
#pragma unroll
    for (int j = 0; j < 32; j += 8)
        t[ty + j][tx] = in[(size_t)(r0 + ty + j) * C + (c0 + tx)];
    __syncthreads();
#pragma unroll
    for (int j = 0; j < 32; j += 8)
        out[(size_t)(c0 + ty + j) * R + (r0 + tx)] = f2bf(t[tx][ty + j]);
}

// ---------- GEMM core ----------
__device__ __forceinline__ void gemm_core(const __bf16* __restrict__ A, const __bf16* __restrict__ Bt,
                                          int K, int m0, int n0r,
                                          __bf16* As, __bf16* Bs, f32x4 (&acc)[4][4], int tid) {
    const int lane = tid & 63, w = tid >> 6;
    const int wr = w >> 1, wc = w & 1;
    const int r = lane & 15, g = lane >> 4;

    for (int k0 = 0; k0 < K; k0 += 64) {
#pragma unroll
        for (int i = 0; i < 4; ++i) {
            int cb = i * 256 + w * 64;        // wave-uniform chunk base
            int chunk = cb + lane;
            int row = chunk >> 3, cc = chunk & 7;
            gload16(A + (size_t)(m0 + row) * K + k0 + cc * 8, As + cb * 8);
            gload16(Bt + (size_t)(n0r + row) * K + k0 + cc * 8, Bs + cb * 8);
        }
        __syncthreads();
        bf16x8 af[4][2], bfr[4][2];
#pragma unroll
        for (int mf = 0; mf < 4; ++mf)
#pragma unroll
            for (int kk = 0; kk < 2; ++kk)
                af[mf][kk] = *(const bf16x8*)(As + (wr * 64 + mf * 16 + r) * 64 + kk * 32 + g * 8);
#pragma unroll
        for (int nf = 0; nf < 4; ++nf)
#pragma unroll
            for (int kk = 0; kk < 2; ++kk)
                bfr[nf][kk] = *(const bf16x8*)(Bs + (wc * 64 + nf * 16 + r) * 64 + kk * 32 + g * 8);
#pragma unroll
        for (int mf = 0; mf < 4; ++mf)
#pragma unroll
            for (int nf = 0; nf < 4; ++nf)
#pragma unroll
                for (int kk = 0; kk < 2; ++kk)
                    acc[mf][nf] = __builtin_amdgcn_mfma_f32_16x16x32_bf16(
                        af[mf][kk], bfr[nf][kk], acc[mf][nf], 0, 0, 0);
        __syncthreads();
    }
}

// ---------- QKV projection ----------
// V written BLOCK-TILED: Vblk[b][kvh][s>>6][d][s&63] -> each 64-key tile contiguous 8KB
__global__ __launch_bounds__(256) void gemm_qkv_kernel(
    const __bf16* __restrict__ xb, const __bf16* __restrict__ wqt,
    const __bf16* __restrict__ wkt, const __bf16* __restrict__ wvt,
    const float* __restrict__ bq, const float* __restrict__ bk, const float* __restrict__ bv,
    __bf16* __restrict__ Qb, __bf16* __restrict__ Kb, __bf16* __restrict__ Vblk) {
    __shared__ __align__(16) __bf16 As[128 * 64];
    __shared__ __align__(16) __bf16 Bs[128 * 64];
    int tid = threadIdx.x;
    int n0 = blockIdx.x * 128, m0 = blockIdx.y * 128;

    const __bf16* Bt; int n0r; const float* bias; int mode;
    if (n0 < 1024)      { Bt = wqt; n0r = n0;        bias = bq; mode = 0; }
    else if (n0 < 1280) { Bt = wkt; n0r = n0 - 1024; bias = bk; mode = 1; }
    else                { Bt = wvt; n0r = n0 - 1280; bias = bv; mode = 2; }

    f32x4 acc[4][4];
    f32x4 z = {0.f, 0.f, 0.f, 0.f};
#pragma unroll
    for (int i = 0; i < 4; ++i)
#pragma unroll
        for (int j = 0; j < 4; ++j) acc[i][j] = z;

    gemm_core(xb, Bt, EMB, m0, n0r, As, Bs, acc, tid);

    const int lane = tid & 63, w = tid >> 6;
    const int wr = w >> 1, wc = w & 1, r = lane & 15, g = lane >> 4;
#pragma unroll
    for (int nf = 0; nf < 4; ++nf) {
        int nn = n0r + wc * 64 + nf * 16 + r;
        float bb = bias[nn];
        int hh = nn >> 6, dd = nn & 63;
        if (mode == 2) {
            // block-tiled V: [s>>6][d][s&63]; 4 consecutive s -> 8B store within one tile row
#pragma unroll
            for (int mf = 0; mf < 4; ++mf) {
                int s0 = m0 + wr * 64 + mf * 16 + g * 4;
                int bi = s0 >> 11, s = s0 & 2047;
                bf16x4 pk;
#pragma unroll
                for (int reg = 0; reg < 4; ++reg) pk[reg] = (__bf16)(acc[mf][nf][reg] + bb);
                *reinterpret_cast<bf16x4*>(Vblk + (size_t)(bi * NKV + hh) * (S_LEN * HD)
                                           + (s >> 6) * 4096 + dd * 64 + (s & 63)) = pk;
            }
        } else {
#pragma unroll
            for (int mf = 0; mf < 4; ++mf)
#pragma unroll
                for (int reg = 0; reg < 4; ++reg) {
                    int m = m0 + wr * 64 + mf * 16 + g * 4 + reg;
                    int bi = m >> 11, s = m & 2047;
                    __bf16 o = (__bf16)(acc[mf][nf][reg] + bb);
                    if (mode == 0)
                        Qb[((size_t)(bi * NH + hh) * S_LEN + s) * HD + dd] = o;
                    else
                        Kb[((size_t)(bi * NKV + hh) * S_LEN + s) * HD + dd] = o;
                }
        }
    }
}

// ---------- sliding-window flash attention ----------
// LDS-staged K/V tiles (coalesced global_load_lds, 4x dedup across waves),
// XOR-swizzled via pre-swizzled global source + swizzled ds_read (both-sides rule).
// 2-phase pipeline: stage(t+1) -> compute(t) -> barrier.
// grid (32, 16, 2); block 256 = 4 waves; wave = 16 query rows; key tiles of 64
__global__ __launch_bounds__(256, 3) void attn_kernel(const __bf16* __restrict__ Qb,
                                                      const __bf16* __restrict__ Kb,
                                                      const __bf16* __restrict__ Vblk,
                                                      __bf16* __restrict__ ctx) {
    __shared__ __align__(16) __bf16 Ks[2][64 * 64];      // [buf][row=key][d]  8KB each
    __shared__ __align__(16) __bf16 Vs[2][64 * 64];      // [buf][row=d][key]  8KB each
    __shared__ __align__(16) __bf16 Plds[4][16 * PPAD];  // per-wave P [q=16][k=64 pad]
    const int tid = threadIdx.x;
    const int lane = tid & 63, w = tid >> 6;
    const int r = lane & 15, g = lane >> 4;
    const int q0 = blockIdx.x * 64;
    const int h = blockIdx.y, b = blockIdx.z;
    const int kvh = h >> 2;
    const __bf16* Qw = Qb + ((size_t)(b * NH + h) * S_LEN + q0 + w * 16) * HD;
    const __bf16* Kh = Kb + (size_t)(b * NKV + kvh) * S_LEN * HD;
    const __bf16* Vh = Vblk + (size_t)(b * NKV + kvh) * S_LEN * HD;
    __bf16* Pw = &Plds[w][0];

    // staging: wave-call j = w*2+i covers 16B-chunks [j*64, j*64+64); chunk n -> lds row n>>3,
    // lds chunk n&7 holds global chunk (n&7)^(row&7)  (inverse-swizzled source)
    const int n0s = w * 128 + lane;          // j = w*2
    const int n1s = n0s + 64;                // j = w*2+1
    const int srcoff0 = (n0s >> 3) * 64 + (((n0s & 7) ^ ((n0s >> 3) & 7)) * 8);
    const int srcoff1 = (n1s >> 3) * 64 + (((n1s & 7) ^ ((n1s >> 3) & 7)) * 8);
    const int dst0 = (w * 2) * 512;          // element offset of call j's 1KB segment
    const int dst1 = dst0 + 512;

    auto stage = [&](int buf, int kbase) {
        const __bf16* Kt = Kh + (size_t)kbase * 64;   // contiguous 8KB tile
        const __bf16* Vt = Vh + (size_t)kbase * 64;   // contiguous 8KB tile (block-tiled layout)
        gload16(Kt + srcoff0, &Ks[buf][dst0]);
        gload16(Kt + srcoff1, &Ks[buf][dst1]);
        gload16(Vt + srcoff0, &Vs[buf][dst0]);
        gload16(Vt + srcoff1, &Vs[buf][dst1]);
    };

    // fragment-read swizzle: want chunk cw = kk*4+g of row -> lds chunk cw ^ (row&7); row&7 == r&7
    const int swz0 = ((0 * 4 + g) ^ (r & 7)) * 8;
    const int swz1 = ((1 * 4 + g) ^ (r & 7)) * 8;

    // Q fragment (B-operand): B[col=q=r][k on g]
    bf16x8 qf[2];
#pragma unroll
    for (int kk = 0; kk < 2; ++kk)
        qf[kk] = *(const bf16x8*)(Qw + r * 64 + kk * 32 + g * 8);

    f32x4 z = {0.f, 0.f, 0.f, 0.f};
    f32x4 o[4];
#pragma unroll
    for (int i = 0; i < 4; ++i) o[i] = z;
    float psum = 0.f;

    const float SC = 0.18033688011112042f;   // D^-0.5 * log2(e)
    const int iq = q0 + w * 16 + r;          // this lane's query index (lane-constant)

    auto tile = [&](int buf, int kbase, bool masked) {
        const __bf16* Kl = &Ks[buf][0];
        const __bf16* Vl = &Vs[buf][0];
        // K fragment (A-operand): A[row=key=r][k on g]
        bf16x8 kf[4][2];
#pragma unroll
        for (int nf = 0; nf < 4; ++nf) {
            kf[nf][0] = *(const bf16x8*)(Kl + nf * 1024 + r * 64 + swz0);
            kf[nf][1] = *(const bf16x8*)(Kl + nf * 1024 + r * 64 + swz1);
        }
        // QK^T swapped: sa[nf][reg] = S[key = kbase + nf*16 + g*4 + reg][q = r]
        f32x4 sa[4];
#pragma unroll
        for (int nf = 0; nf < 4; ++nf) sa[nf] = z;
#pragma unroll
        for (int nf = 0; nf < 4; ++nf)
#pragma unroll
            for (int kk = 0; kk < 2; ++kk)
                sa[nf] = __builtin_amdgcn_mfma_f32_16x16x32_bf16(kf[nf][kk], qf[kk], sa[nf], 0, 0, 0);
        // exp; P[q=r][k] write: 4 consecutive k per nf -> 8B packed
#pragma unroll
        for (int nf = 0; nf < 4; ++nf) {
            int jb = kbase + nf * 16 + g * 4;
            bf16x4 pk;
#pragma unroll
            for (int reg = 0; reg < 4; ++reg) {
                float x = sa[nf][reg] * SC;
                if (masked) {
                    uint32_t d = (uint32_t)(iq - (jb + reg));   // valid iff 0 <= iq-j <= WIN
                    x = (d <= (uint32_t)WIN) ? x : -1e30f;
                }
                float e = fast_exp2(x);
                psum += e;
                pk[reg] = (__bf16)e;
            }
            *reinterpret_cast<bf16x4*>(Pw + r * PPAD + nf * 16 + g * 4) = pk;
        }
        // V^T fragment (A-operand): A[row=d=r][k on g]
        bf16x8 vf[4][2];
#pragma unroll
        for (int nf2 = 0; nf2 < 4; ++nf2) {
            vf[nf2][0] = *(const bf16x8*)(Vl + nf2 * 1024 + r * 64 + swz0);
            vf[nf2][1] = *(const bf16x8*)(Vl + nf2 * 1024 + r * 64 + swz1);
        }
        // PV: o[nf2] = mfma(V^T frag, P frag)
#pragma unroll
        for (int kk2 = 0; kk2 < 2; ++kk2) {
            bf16x8 pa = *(const bf16x8*)(Pw + r * PPAD + kk2 * 32 + g * 8);
#pragma unroll
            for (int nf2 = 0; nf2 < 4; ++nf2)
                o[nf2] = __builtin_amdgcn_mfma_f32_16x16x32_bf16(vf[nf2][kk2], pa, o[nf2], 0, 0, 0);
        }
    };

    const int kb0 = (q0 >= 256) ? (q0 - 256) : 0;
    const int nt = (q0 - kb0) / 64 + 1;        // 1..5 tiles
    stage(0, kb0);
    __syncthreads();
    for (int t = 0; t < nt; ++t) {
        int kbase = kb0 + t * 64;
        if (t + 1 < nt) stage((t + 1) & 1, kbase + 64);
        bool masked = (kbase == q0) || (q0 >= 256 && t == 0);
        tile(t & 1, kbase, masked);
        __syncthreads();
    }

    // row-sum: reduce over the 4 g-groups (q = r is lane-constant)
    psum += __shfl_xor(psum, 16, 64);
    psum += __shfl_xor(psum, 32, 64);
    float linv = 1.0f / psum;

    // o[nf2][reg] = out[d = nf2*16 + g*4 + reg][q = r]; 4 consecutive d -> 8B store
    int s = q0 + w * 16 + r;
#pragma unroll
    for (int nf2 = 0; nf2 < 4; ++nf2) {
        bf16x4 pk;
#pragma unroll
        for (int reg = 0; reg < 4; ++reg) pk[reg] = (__bf16)(o[nf2][reg] * linv);
        *reinterpret_cast<bf16x4*>(ctx + ((size_t)(b * S_LEN + s)) * EMB + h * 64 + nf2 * 16 + g * 4) = pk;
    }
}

// ---------- output projection ----------
__global__ __launch_bounds__(256) void gemm_out_kernel(const __bf16* __restrict__ ctxb,
                                                       const __bf16* __restrict__ wot,
                                                       const float* __restrict__ bo,
                                                       float* __restrict__ out) {
    __shared__ __align__(16) __bf16 As[128 * 64];
    __shared__ __align__(16) __bf16 Bs[128 * 64];
    int tid = threadIdx.x;
    int n0 = blockIdx.x * 128, m0 = blockIdx.y * 128;

    f32x4 acc[4][4];
    f32x4 z = {0.f, 0.f, 0.f, 0.f};
#pragma unroll
    for (int i = 0; i < 4; ++i)
#pragma unroll
        for (int j = 0; j < 4; ++j) acc[i][j] = z;

    gemm_core(ctxb, wot, EMB, m0, n0, As, Bs, acc, tid);

    const int lane = tid & 63, w = tid >> 6;
    const int wr = w >> 1, wc = w & 1, r = lane & 15, g = lane >> 4;
#pragma unroll
    for (int nf = 0; nf < 4; ++nf) {
        int n = n0 + wc * 64 + nf * 16 + r;
        float bb = bo[n];
#pragma unroll
        for (int mf = 0; mf < 4; ++mf)
#pragma unroll
            for (int reg = 0; reg < 4; ++reg) {
                int m = m0 + wr * 64 + mf * 16 + g * 4 + reg;
                out[(size_t)m * EMB + n] = acc[mf][nf][reg] + bb;
            }
    }
}

// ---------- launch ----------
extern "C" void kernel_launch(void* const* d_in, const int* in_sizes, int n_in,
                              void* d_out, int out_size, void* d_ws, size_t ws_size,
                              hipStream_t stream) {
    const float* x  = (const float*)d_in[0];
    const float* wq = (const float*)d_in[1];
    const float* bq = (const float*)d_in[2];
    const float* wk = (const float*)d_in[3];
    const float* bk = (const float*)d_in[4];
    const float* wv = (const float*)d_in[5];
    const float* bv = (const float*)d_in[6];
    const float* wo = (const float*)d_in[7];
    const float* bo = (const float*)d_in[8];
    float* out = (float*)d_out;

    char* ws = (char*)d_ws;
    __bf16* xb   = (__bf16*)ws;          ws += (size_t)MROWS * EMB * 2;           // 8 MB
    __bf16* wqt  = (__bf16*)ws;          ws += (size_t)EMB * EMB * 2;             // 2 MB
    __bf16* wkt  = (__bf16*)ws;          ws += (size_t)256 * EMB * 2;             // 0.5 MB
    __bf16* wvt  = (__bf16*)ws;          ws += (size_t)256 * EMB * 2;             // 0.5 MB
    __bf16* wot  = (__bf16*)ws;          ws += (size_t)EMB * EMB * 2;             // 2 MB
    __bf16* Qb   = (__bf16*)ws;          ws += (size_t)NB * NH * S_LEN * HD * 2;  // 8 MB
    __bf16* Kb   = (__bf16*)ws;          ws += (size_t)NB * NKV * S_LEN * HD * 2; // 2 MB
    __bf16* Vblk = (__bf16*)ws;          ws += (size_t)NB * NKV * S_LEN * HD * 2; // 2 MB
    __bf16* ctx  = (__bf16*)ws;          ws += (size_t)MROWS * EMB * 2;           // 8 MB

    cvt_kernel<<<2048, 256, 0, stream>>>(x, (u16*)xb, (MROWS * EMB) / 8);
    transpose_cvt_kernel<<<dim3(32, 32), dim3(32, 8), 0, stream>>>(wq, (u16*)wqt, EMB, EMB);
    transpose_cvt_kernel<<<dim3(8, 32),  dim3(32, 8), 0, stream>>>(wk, (u16*)wkt, EMB, 256);
    transpose_cvt_kernel<<<dim3(8, 32),  dim3(32, 8), 0, stream>>>(wv, (u16*)wvt, EMB, 256);
    transpose_cvt_kernel<<<dim3(32, 32), dim3(32, 8), 0, stream>>>(wo, (u16*)wot, EMB, EMB);

    gemm_qkv_kernel<<<dim3(12, 32), 256, 0, stream>>>(xb, wqt, wkt, wvt, bq, bk, bv, Qb, Kb, Vblk);
    attn_kernel<<<dim3(32, 16, 2), 256, 0, stream>>>(Qb, Kb, Vblk, ctx);
    gemm_out_kernel<<<dim3(8, 32), 256, 0, stream>>>(ctx, wot, bo, out);
}

// Round 6
// 74.096 us; speedup vs baseline: 1.5917x; 1.1885x over previous
//
#include <hip/hip_runtime.h>
#include <stdint.h>

typedef unsigned short u16;
typedef __attribute__((ext_vector_type(8))) __bf16 bf16x8;
typedef __attribute__((ext_vector_type(4))) __bf16 bf16x4;
typedef __attribute__((ext_vector_type(4))) float f32x4;

#define S_LEN 2048
#define EMB   1024
#define NH    16
#define NKV   4
#define HD    64
#define WIN   256
#define NB    2
#define MROWS (NB * S_LEN)   // 4096
#define PPAD  72             // P LDS row stride (elements)

// ---------- helpers ----------
__device__ __forceinline__ u16 f2bf(float f) {
    uint32_t u = __float_as_uint(f);
    uint32_t r = (u + 0x7FFFu + ((u >> 16) & 1u)) >> 16;   // RNE
    return (u16)r;
}

__device__ __forceinline__ float fast_exp2(float x) {
#if __has_builtin(__builtin_amdgcn_exp2f)
    return __builtin_amdgcn_exp2f(x);
#else
    float r; asm("v_exp_f32 %0, %1" : "=v"(r) : "v"(x)); return r;
#endif
}

__device__ __forceinline__ void gload16(const void* g, void* l) {
    __builtin_amdgcn_global_load_lds(
        (const __attribute__((address_space(1))) uint32_t*)(uintptr_t)g,
        (__attribute__((address_space(3))) uint32_t*)(uintptr_t)l,
        16, 0, 0);
}

// ---------- fused prep: x->bf16 + 4 weight transposes ----------
// grid 4608 x 256: [0,2048) cvt x; [2048,3072) wq^T; [3072,3328) wk^T;
//                  [3328,3584) wv^T; [3584,4608) wo^T
__device__ __forceinline__ void transpose_job(const float* __restrict__ in,
                                              u16* __restrict__ out,
                                              int R, int C, int bx, int by, int tid) {
    __shared__ float t[32][33];
    int c0 = bx * 32, r0 = by * 32;
    int tx = tid & 31, ty = tid >> 5;   // (32, 8)
#pragma unroll
    for (int j = 0; j < 32; j += 8)
        t[ty + j][tx] = in[(size_t)(r0 + ty + j) * C + (c0 + tx)];
    __syncthreads();
#pragma unroll
    for (int j = 0; j < 32; j += 8)
        out[(size_t)(c0 + ty + j) * R + (r0 + tx)] = f2bf(t[tx][ty + j]);
}

__global__ __launch_bounds__(256) void prep_kernel(
    const float* __restrict__ x,  const float* __restrict__ wq,
    const float* __restrict__ wk, const float* __restrict__ wv,
    const float* __restrict__ wo,
    u16* __restrict__ xb, u16* __restrict__ wqt, u16* __restrict__ wkt,
    u16* __restrict__ wvt, u16* __restrict__ wot) {
    int bid = blockIdx.x, tid = threadIdx.x;
    if (bid < 2048) {
        int i = bid * 256 + tid;                       // 8 elems each
        const float4* p = (const float4*)x + (size_t)i * 2;
        float4 a = p[0], b = p[1];
        uint4 q;
        q.x = f2bf(a.x) | ((uint32_t)f2bf(a.y) << 16);
        q.y = f2bf(a.z) | ((uint32_t)f2bf(a.w) << 16);
        q.z = f2bf(b.x) | ((uint32_t)f2bf(b.y) << 16);
        q.w = f2bf(b.z) | ((uint32_t)f2bf(b.w) << 16);
        ((uint4*)xb)[i] = q;
    } else if (bid < 3072) {
        int lb = bid - 2048;  transpose_job(wq, wqt, EMB, EMB, lb & 31, lb >> 5, tid);
    } else if (bid < 3328) {
        int lb = bid - 3072;  transpose_job(wk, wkt, EMB, 256, lb & 7, lb >> 3, tid);
    } else if (bid < 3584) {
        int lb = bid - 3328;  transpose_job(wv, wvt, EMB, 256, lb & 7, lb >> 3, tid);
    } else {
        int lb = bid - 3584;  transpose_job(wo, wot, EMB, EMB, lb & 31, lb >> 5, tid);
    }
}

// ---------- GEMM core: BM=64 x BN=128, BK=64, 4 waves (2x2), wave -> 32x64 ----------
__device__ __forceinline__ void gemm_core64(const __bf16* __restrict__ A, const __bf16* __restrict__ Bt,
                                            int K, int m0, int n0r,
                                            __bf16* As, __bf16* Bs, f32x4 (&acc)[2][4], int tid) {
    const int lane = tid & 63, w = tid >> 6;
    const int wr = w >> 1, wc = w & 1;
    const int r = lane & 15, g = lane >> 4;

    for (int k0 = 0; k0 < K; k0 += 64) {
        // A tile 64x64 (8KB): 8 wave-calls -> 2 per wave
#pragma unroll
        for (int i = 0; i < 2; ++i) {
            int chunk = (w * 2 + i) * 64 + lane;
            int row = chunk >> 3, cc = chunk & 7;
            gload16(A + (size_t)(m0 + row) * K + k0 + cc * 8, As + chunk * 8);
        }
        // B tile 128x64 (16KB): 16 wave-calls -> 4 per wave
#pragma unroll
        for (int i = 0; i < 4; ++i) {
            int chunk = (w * 4 + i) * 64 + lane;
            int row = chunk >> 3, cc = chunk & 7;
            gload16(Bt + (size_t)(n0r + row) * K + k0 + cc * 8, Bs + chunk * 8);
        }
        __syncthreads();
        bf16x8 af[2][2], bfr[4][2];
#pragma unroll
        for (int mf = 0; mf < 2; ++mf)
#pragma unroll
            for (int kk = 0; kk < 2; ++kk)
                af[mf][kk] = *(const bf16x8*)(As + (wr * 32 + mf * 16 + r) * 64 + kk * 32 + g * 8);
#pragma unroll
        for (int nf = 0; nf < 4; ++nf)
#pragma unroll
            for (int kk = 0; kk < 2; ++kk)
                bfr[nf][kk] = *(const bf16x8*)(Bs + (wc * 64 + nf * 16 + r) * 64 + kk * 32 + g * 8);
#pragma unroll
        for (int mf = 0; mf < 2; ++mf)
#pragma unroll
            for (int nf = 0; nf < 4; ++nf)
#pragma unroll
                for (int kk = 0; kk < 2; ++kk)
                    acc[mf][nf] = __builtin_amdgcn_mfma_f32_16x16x32_bf16(
                        af[mf][kk], bfr[nf][kk], acc[mf][nf], 0, 0, 0);
        __syncthreads();
    }
}

// ---------- QKV projection ----------
// grid (12, 64): n-tile 0-7 -> Q, 8-9 -> K, 10-11 -> V ; m-tile = 64 rows
__global__ __launch_bounds__(256, 4) void gemm_qkv_kernel(
    const __bf16* __restrict__ xb, const __bf16* __restrict__ wqt,
    const __bf16* __restrict__ wkt, const __bf16* __restrict__ wvt,
    const float* __restrict__ bq, const float* __restrict__ bk, const float* __restrict__ bv,
    __bf16* __restrict__ Qb, __bf16* __restrict__ Kb, __bf16* __restrict__ Vblk) {
    __shared__ __align__(16) __bf16 As[64 * 64];
    __shared__ __align__(16) __bf16 Bs[128 * 64];
    int tid = threadIdx.x;
    int n0 = blockIdx.x * 128, m0 = blockIdx.y * 64;

    const __bf16* Bt; int n0r; const float* bias; int mode;
    if (n0 < 1024)      { Bt = wqt; n0r = n0;        bias = bq; mode = 0; }
    else if (n0 < 1280) { Bt = wkt; n0r = n0 - 1024; bias = bk; mode = 1; }
    else                { Bt = wvt; n0r = n0 - 1280; bias = bv; mode = 2; }

    f32x4 acc[2][4];
    f32x4 z = {0.f, 0.f, 0.f, 0.f};
#pragma unroll
    for (int i = 0; i < 2; ++i)
#pragma unroll
        for (int j = 0; j < 4; ++j) acc[i][j] = z;

    gemm_core64(xb, Bt, EMB, m0, n0r, As, Bs, acc, tid);

    const int lane = tid & 63, w = tid >> 6;
    const int wr = w >> 1, wc = w & 1, r = lane & 15, g = lane >> 4;
#pragma unroll
    for (int nf = 0; nf < 4; ++nf) {
        int nn = n0r + wc * 64 + nf * 16 + r;
        float bb = bias[nn];
        int hh = nn >> 6, dd = nn & 63;
        if (mode == 2) {
            // block-tiled V: [s>>6][d][s&63]; 4 consecutive s -> 8B store
#pragma unroll
            for (int mf = 0; mf < 2; ++mf) {
                int s0 = m0 + wr * 32 + mf * 16 + g * 4;
                int bi = s0 >> 11, s = s0 & 2047;
                bf16x4 pk;
#pragma unroll
                for (int reg = 0; reg < 4; ++reg) pk[reg] = (__bf16)(acc[mf][nf][reg] + bb);
                *reinterpret_cast<bf16x4*>(Vblk + (size_t)(bi * NKV + hh) * (S_LEN * HD)
                                           + (s >> 6) * 4096 + dd * 64 + (s & 63)) = pk;
            }
        } else {
#pragma unroll
            for (int mf = 0; mf < 2; ++mf)
#pragma unroll
                for (int reg = 0; reg < 4; ++reg) {
                    int m = m0 + wr * 32 + mf * 16 + g * 4 + reg;
                    int bi = m >> 11, s = m & 2047;
                    __bf16 o = (__bf16)(acc[mf][nf][reg] + bb);
                    if (mode == 0)
                        Qb[((size_t)(bi * NH + hh) * S_LEN + s) * HD + dd] = o;
                    else
                        Kb[((size_t)(bi * NKV + hh) * S_LEN + s) * HD + dd] = o;
                }
        }
    }
}

// ---------- sliding-window flash attention (unchanged from r5) ----------
__global__ __launch_bounds__(256, 3) void attn_kernel(const __bf16* __restrict__ Qb,
                                                      const __bf16* __restrict__ Kb,
                                                      const __bf16* __restrict__ Vblk,
                                                      __bf16* __restrict__ ctx) {
    __shared__ __align__(16) __bf16 Ks[2][64 * 64];      // [buf][row=key][d]  8KB each
    __shared__ __align__(16) __bf16 Vs[2][64 * 64];      // [buf][row=d][key]  8KB each
    __shared__ __align__(16) __bf16 Plds[4][16 * PPAD];  // per-wave P [q=16][k=64 pad]
    const int tid = threadIdx.x;
    const int lane = tid & 63, w = tid >> 6;
    const int r = lane & 15, g = lane >> 4;
    const int q0 = blockIdx.x * 64;
    const int h = blockIdx.y, b = blockIdx.z;
    const int kvh = h >> 2;
    const __bf16* Qw = Qb + ((size_t)(b * NH + h) * S_LEN + q0 + w * 16) * HD;
    const __bf16* Kh = Kb + (size_t)(b * NKV + kvh) * S_LEN * HD;
    const __bf16* Vh = Vblk + (size_t)(b * NKV + kvh) * S_LEN * HD;
    __bf16* Pw = &Plds[w][0];

    const int n0s = w * 128 + lane;
    const int n1s = n0s + 64;
    const int srcoff0 = (n0s >> 3) * 64 + (((n0s & 7) ^ ((n0s >> 3) & 7)) * 8);
    const int srcoff1 = (n1s >> 3) * 64 + (((n1s & 7) ^ ((n1s >> 3) & 7)) * 8);
    const int dst0 = (w * 2) * 512;
    const int dst1 = dst0 + 512;

    auto stage = [&](int buf, int kbase) {
        const __bf16* Kt = Kh + (size_t)kbase * 64;
        const __bf16* Vt = Vh + (size_t)kbase * 64;
        gload16(Kt + srcoff0, &Ks[buf][dst0]);
        gload16(Kt + srcoff1, &Ks[buf][dst1]);
        gload16(Vt + srcoff0, &Vs[buf][dst0]);
        gload16(Vt + srcoff1, &Vs[buf][dst1]);
    };

    const int swz0 = ((0 * 4 + g) ^ (r & 7)) * 8;
    const int swz1 = ((1 * 4 + g) ^ (r & 7)) * 8;

    bf16x8 qf[2];
#pragma unroll
    for (int kk = 0; kk < 2; ++kk)
        qf[kk] = *(const bf16x8*)(Qw + r * 64 + kk * 32 + g * 8);

    f32x4 z = {0.f, 0.f, 0.f, 0.f};
    f32x4 o[4];
#pragma unroll
    for (int i = 0; i < 4; ++i) o[i] = z;
    float psum = 0.f;

    const float SC = 0.18033688011112042f;   // D^-0.5 * log2(e)
    const int iq = q0 + w * 16 + r;

    auto tile = [&](int buf, int kbase, bool masked) {
        const __bf16* Kl = &Ks[buf][0];
        const __bf16* Vl = &Vs[buf][0];
        bf16x8 kf[4][2];
#pragma unroll
        for (int nf = 0; nf < 4; ++nf) {
            kf[nf][0] = *(const bf16x8*)(Kl + nf * 1024 + r * 64 + swz0);
            kf[nf][1] = *(const bf16x8*)(Kl + nf * 1024 + r * 64 + swz1);
        }
        f32x4 sa[4];
#pragma unroll
        for (int nf = 0; nf < 4; ++nf) sa[nf] = z;
#pragma unroll
        for (int nf = 0; nf < 4; ++nf)
#pragma unroll
            for (int kk = 0; kk < 2; ++kk)
                sa[nf] = __builtin_amdgcn_mfma_f32_16x16x32_bf16(kf[nf][kk], qf[kk], sa[nf], 0, 0, 0);
#pragma unroll
        for (int nf = 0; nf < 4; ++nf) {
            int jb = kbase + nf * 16 + g * 4;
            bf16x4 pk;
#pragma unroll
            for (int reg = 0; reg < 4; ++reg) {
                float x = sa[nf][reg] * SC;
                if (masked) {
                    uint32_t d = (uint32_t)(iq - (jb + reg));
                    x = (d <= (uint32_t)WIN) ? x : -1e30f;
                }
                float e = fast_exp2(x);
                psum += e;
                pk[reg] = (__bf16)e;
            }
            *reinterpret_cast<bf16x4*>(Pw + r * PPAD + nf * 16 + g * 4) = pk;
        }
        bf16x8 vf[4][2];
#pragma unroll
        for (int nf2 = 0; nf2 < 4; ++nf2) {
            vf[nf2][0] = *(const bf16x8*)(Vl + nf2 * 1024 + r * 64 + swz0);
            vf[nf2][1] = *(const bf16x8*)(Vl + nf2 * 1024 + r * 64 + swz1);
        }
#pragma unroll
        for (int kk2 = 0; kk2 < 2; ++kk2) {
            bf16x8 pa = *(const bf16x8*)(Pw + r * PPAD + kk2 * 32 + g * 8);
#pragma unroll
            for (int nf2 = 0; nf2 < 4; ++nf2)
                o[nf2] = __builtin_amdgcn_mfma_f32_16x16x32_bf16(vf[nf2][kk2], pa, o[nf2], 0, 0, 0);
        }
    };

    const int kb0 = (q0 >= 256) ? (q0 - 256) : 0;
    const int nt = (q0 - kb0) / 64 + 1;
    stage(0, kb0);
    __syncthreads();
    for (int t = 0; t < nt; ++t) {
        int kbase = kb0 + t * 64;
        if (t + 1 < nt) stage((t + 1) & 1, kbase + 64);
        bool masked = (kbase == q0) || (q0 >= 256 && t == 0);
        tile(t & 1, kbase, masked);
        __syncthreads();
    }

    psum += __shfl_xor(psum, 16, 64);
    psum += __shfl_xor(psum, 32, 64);
    float linv = 1.0f / psum;

    int s = q0 + w * 16 + r;
#pragma unroll
    for (int nf2 = 0; nf2 < 4; ++nf2) {
        bf16x4 pk;
#pragma unroll
        for (int reg = 0; reg < 4; ++reg) pk[reg] = (__bf16)(o[nf2][reg] * linv);
        *reinterpret_cast<bf16x4*>(ctx + ((size_t)(b * S_LEN + s)) * EMB + h * 64 + nf2 * 16 + g * 4) = pk;
    }
}

// ---------- output projection ----------
__global__ __launch_bounds__(256, 4) void gemm_out_kernel(const __bf16* __restrict__ ctxb,
                                                          const __bf16* __restrict__ wot,
                                                          const float* __restrict__ bo,
                                                          float* __restrict__ out) {
    __shared__ __align__(16) __bf16 As[64 * 64];
    __shared__ __align__(16) __bf16 Bs[128 * 64];
    int tid = threadIdx.x;
    int n0 = blockIdx.x * 128, m0 = blockIdx.y * 64;

    f32x4 acc[2][4];
    f32x4 z = {0.f, 0.f, 0.f, 0.f};
#pragma unroll
    for (int i = 0; i < 2; ++i)
#pragma unroll
        for (int j = 0; j < 4; ++j) acc[i][j] = z;

    gemm_core64(ctxb, wot, EMB, m0, n0, As, Bs, acc, tid);

    const int lane = tid & 63, w = tid >> 6;
    const int wr = w >> 1, wc = w & 1, r = lane & 15, g = lane >> 4;
#pragma unroll
    for (int nf = 0; nf < 4; ++nf) {
        int n = n0 + wc * 64 + nf * 16 + r;
        float bb = bo[n];
#pragma unroll
        for (int mf = 0; mf < 2; ++mf)
#pragma unroll
            for (int reg = 0; reg < 4; ++reg) {
                int m = m0 + wr * 32 + mf * 16 + g * 4 + reg;
                out[(size_t)m * EMB + n] = acc[mf][nf][reg] + bb;
            }
    }
}

// ---------- launch ----------
extern "C" void kernel_launch(void* const* d_in, const int* in_sizes, int n_in,
                              void* d_out, int out_size, void* d_ws, size_t ws_size,
                              hipStream_t stream) {
    const float* x  = (const float*)d_in[0];
    const float* wq = (const float*)d_in[1];
    const float* bq = (const float*)d_in[2];
    const float* wk = (const float*)d_in[3];
    const float* bk = (const float*)d_in[4];
    const float* wv = (const float*)d_in[5];
    const float* bv = (const float*)d_in[6];
    const float* wo = (const float*)d_in[7];
    const float* bo = (const float*)d_in[8];
    float* out = (float*)d_out;

    char* ws = (char*)d_ws;
    __bf16* xb   = (__bf16*)ws;          ws += (size_t)MROWS * EMB * 2;           // 8 MB
    __bf16* wqt  = (__bf16*)ws;          ws += (size_t)EMB * EMB * 2;             // 2 MB
    __bf16* wkt  = (__bf16*)ws;          ws += (size_t)256 * EMB * 2;             // 0.5 MB
    __bf16* wvt  = (__bf16*)ws;          ws += (size_t)256 * EMB * 2;             // 0.5 MB
    __bf16* wot  = (__bf16*)ws;          ws += (size_t)EMB * EMB * 2;             // 2 MB
    __bf16* Qb   = (__bf16*)ws;          ws += (size_t)NB * NH * S_LEN * HD * 2;  // 8 MB
    __bf16* Kb   = (__bf16*)ws;          ws += (size_t)NB * NKV * S_LEN * HD * 2; // 2 MB
    __bf16* Vblk = (__bf16*)ws;          ws += (size_t)NB * NKV * S_LEN * HD * 2; // 2 MB
    __bf16* ctx  = (__bf16*)ws;          ws += (size_t)MROWS * EMB * 2;           // 8 MB

    prep_kernel<<<4608, 256, 0, stream>>>(x, wq, wk, wv, wo,
                                          (u16*)xb, (u16*)wqt, (u16*)wkt, (u16*)wvt, (u16*)wot);
    gemm_qkv_kernel<<<dim3(12, 64), 256, 0, stream>>>(xb, wqt, wkt, wvt, bq, bk, bv, Qb, Kb, Vblk);
    attn_kernel<<<dim3(32, 16, 2), 256, 0, stream>>>(Qb, Kb, Vblk, ctx);
    gemm_out_kernel<<<dim3(8, 64), 256, 0, stream>>>(ctx, wot, bo, out);
}

// Round 7
// 66.513 us; speedup vs baseline: 1.7731x; 1.1140x over previous
//
#include <hip/hip_runtime.h>
#include <stdint.h>

typedef unsigned short u16;
typedef __attribute__((ext_vector_type(8))) __bf16 bf16x8;
typedef __attribute__((ext_vector_type(4))) __bf16 bf16x4;
typedef __attribute__((ext_vector_type(4))) float f32x4;

#define S_LEN 2048
#define EMB   1024
#define NH    16
#define NKV   4
#define HD    64
#define WIN   256
#define NB    2
#define MROWS (NB * S_LEN)   // 4096
#define PPAD  72             // P LDS row stride (elements)

// ---------- helpers ----------
__device__ __forceinline__ u16 f2bf(float f) {
    uint32_t u = __float_as_uint(f);
    uint32_t r = (u + 0x7FFFu + ((u >> 16) & 1u)) >> 16;   // RNE
    return (u16)r;
}

__device__ __forceinline__ float fast_exp2(float x) {
#if __has_builtin(__builtin_amdgcn_exp2f)
    return __builtin_amdgcn_exp2f(x);
#else
    float r; asm("v_exp_f32 %0, %1" : "=v"(r) : "v"(x)); return r;
#endif
}

__device__ __forceinline__ void gload16(const void* g, void* l) {
    __builtin_amdgcn_global_load_lds(
        (const __attribute__((address_space(1))) uint32_t*)(uintptr_t)g,
        (__attribute__((address_space(3))) uint32_t*)(uintptr_t)l,
        16, 0, 0);
}

// ---------- fused prep: x->bf16 + 4 weight transposes ----------
// in [R][C] f32 -> out [C][R] bf16; tile = 64 rows (r) x 32 cols (c)
__device__ __forceinline__ void transpose_job64(const float* __restrict__ in,
                                                u16* __restrict__ out,
                                                int R, int C, int bx, int by, int tid) {
    __shared__ float t[64][33];
    int c0 = bx * 32, r0 = by * 64;
    int tx = tid & 31, ty = tid >> 5;   // (32, 8)
#pragma unroll
    for (int j = 0; j < 64; j += 8)
        t[ty + j][tx] = in[(size_t)(r0 + ty + j) * C + (c0 + tx)];
    __syncthreads();
    // write: lane tx covers r pair (2tx, 2tx+1) packed as u32 -> 128B segments
#pragma unroll
    for (int j = 0; j < 32; j += 8) {
        int c = j + ty;
        uint32_t v = f2bf(t[2 * tx][c]) | ((uint32_t)f2bf(t[2 * tx + 1][c]) << 16);
        *(uint32_t*)(out + (size_t)(c0 + c) * R + r0 + 2 * tx) = v;
    }
}

// grid 3328: [0,2048) x-cvt; [2048,2560) wq^T; [2560,2688) wk^T; [2688,2816) wv^T; [2816,3328) wo^T
__global__ __launch_bounds__(256) void prep_kernel(
    const float* __restrict__ x,  const float* __restrict__ wq,
    const float* __restrict__ wk, const float* __restrict__ wv,
    const float* __restrict__ wo,
    u16* __restrict__ xb, u16* __restrict__ wqt, u16* __restrict__ wkt,
    u16* __restrict__ wvt, u16* __restrict__ wot) {
    int bid = blockIdx.x, tid = threadIdx.x;
    if (bid < 2048) {
        int i = bid * 256 + tid;                       // 8 elems each
        const float4* p = (const float4*)x + (size_t)i * 2;
        float4 a = p[0], b = p[1];
        uint4 q;
        q.x = f2bf(a.x) | ((uint32_t)f2bf(a.y) << 16);
        q.y = f2bf(a.z) | ((uint32_t)f2bf(a.w) << 16);
        q.z = f2bf(b.x) | ((uint32_t)f2bf(b.y) << 16);
        q.w = f2bf(b.z) | ((uint32_t)f2bf(b.w) << 16);
        ((uint4*)xb)[i] = q;
    } else if (bid < 2560) {
        int lb = bid - 2048;  transpose_job64(wq, wqt, EMB, EMB, lb & 31, lb >> 5, tid);
    } else if (bid < 2688) {
        int lb = bid - 2560;  transpose_job64(wk, wkt, EMB, 256, lb & 7, lb >> 3, tid);
    } else if (bid < 2816) {
        int lb = bid - 2688;  transpose_job64(wv, wvt, EMB, 256, lb & 7, lb >> 3, tid);
    } else {
        int lb = bid - 2816;  transpose_job64(wo, wot, EMB, EMB, lb & 31, lb >> 5, tid);
    }
}

// ---------- GEMM core: BM=64 x BN=128, BK=64, 4 waves (2x2), wave -> 32x64 ----------
// 2-phase prefetch pipeline: stage(t+1) -> compute(t) -> barrier (loads fly under MFMA)
__device__ __forceinline__ void gemm_core64(const __bf16* __restrict__ A, const __bf16* __restrict__ Bt,
                                            int K, int m0, int n0r,
                                            __bf16 (*As)[64 * 64], __bf16 (*Bs)[128 * 64],
                                            f32x4 (&acc)[2][4], int tid) {
    const int lane = tid & 63, w = tid >> 6;
    const int wr = w >> 1, wc = w & 1;
    const int r = lane & 15, g = lane >> 4;

    auto stage = [&](int buf, int k0) {
#pragma unroll
        for (int i = 0; i < 2; ++i) {
            int chunk = (w * 2 + i) * 64 + lane;
            int row = chunk >> 3, cc = chunk & 7;
            gload16(A + (size_t)(m0 + row) * K + k0 + cc * 8, &As[buf][(w * 2 + i) * 512]);
        }
#pragma unroll
        for (int i = 0; i < 4; ++i) {
            int chunk = (w * 4 + i) * 64 + lane;
            int row = chunk >> 3, cc = chunk & 7;
            gload16(Bt + (size_t)(n0r + row) * K + k0 + cc * 8, &Bs[buf][(w * 4 + i) * 512]);
        }
    };

    stage(0, 0);
    __syncthreads();
    for (int k0 = 0; k0 < K; k0 += 64) {
        int cur = (k0 >> 6) & 1;
        if (k0 + 64 < K) stage(cur ^ 1, k0 + 64);
        bf16x8 af[2][2], bfr[4][2];
#pragma unroll
        for (int mf = 0; mf < 2; ++mf)
#pragma unroll
            for (int kk = 0; kk < 2; ++kk)
                af[mf][kk] = *(const bf16x8*)(&As[cur][(wr * 32 + mf * 16 + r) * 64 + kk * 32 + g * 8]);
#pragma unroll
        for (int nf = 0; nf < 4; ++nf)
#pragma unroll
            for (int kk = 0; kk < 2; ++kk)
                bfr[nf][kk] = *(const bf16x8*)(&Bs[cur][(wc * 64 + nf * 16 + r) * 64 + kk * 32 + g * 8]);
#pragma unroll
        for (int mf = 0; mf < 2; ++mf)
#pragma unroll
            for (int nf = 0; nf < 4; ++nf)
#pragma unroll
                for (int kk = 0; kk < 2; ++kk)
                    acc[mf][nf] = __builtin_amdgcn_mfma_f32_16x16x32_bf16(
                        af[mf][kk], bfr[nf][kk], acc[mf][nf], 0, 0, 0);
        __syncthreads();
    }
}

// ---------- QKV projection ----------
// 1D grid 768, XCD-swizzled; job: n-tile 0-7 -> Q, 8-9 -> K, 10-11 -> V; m-tile = 64 rows
__global__ __launch_bounds__(256, 3) void gemm_qkv_kernel(
    const __bf16* __restrict__ xb, const __bf16* __restrict__ wqt,
    const __bf16* __restrict__ wkt, const __bf16* __restrict__ wvt,
    const float* __restrict__ bq, const float* __restrict__ bk, const float* __restrict__ bv,
    __bf16* __restrict__ Qb, __bf16* __restrict__ Kb, __bf16* __restrict__ Vblk) {
    __shared__ __align__(16) __bf16 As[2][64 * 64];
    __shared__ __align__(16) __bf16 Bs[2][128 * 64];
    int tid = threadIdx.x;
    int wg = (blockIdx.x & 7) * 96 + (blockIdx.x >> 3);   // 768 = 8 XCD x 96
    int n0 = (wg % 12) * 128, m0 = (wg / 12) * 64;

    const __bf16* Bt; int n0r; const float* bias; int mode;
    if (n0 < 1024)      { Bt = wqt; n0r = n0;        bias = bq; mode = 0; }
    else if (n0 < 1280) { Bt = wkt; n0r = n0 - 1024; bias = bk; mode = 1; }
    else                { Bt = wvt; n0r = n0 - 1280; bias = bv; mode = 2; }

    f32x4 acc[2][4];
    f32x4 z = {0.f, 0.f, 0.f, 0.f};
#pragma unroll
    for (int i = 0; i < 2; ++i)
#pragma unroll
        for (int j = 0; j < 4; ++j) acc[i][j] = z;

    gemm_core64(xb, Bt, EMB, m0, n0r, As, Bs, acc, tid);

    const int lane = tid & 63, w = tid >> 6;
    const int wr = w >> 1, wc = w & 1, r = lane & 15, g = lane >> 4;
#pragma unroll
    for (int nf = 0; nf < 4; ++nf) {
        int nn = n0r + wc * 64 + nf * 16 + r;
        float bb = bias[nn];
        int hh = nn >> 6, dd = nn & 63;
        if (mode == 2) {
            // block-tiled V: [s>>6][d][s&63]; 4 consecutive s -> 8B store
#pragma unroll
            for (int mf = 0; mf < 2; ++mf) {
                int s0 = m0 + wr * 32 + mf * 16 + g * 4;
                int bi = s0 >> 11, s = s0 & 2047;
                bf16x4 pk;
#pragma unroll
                for (int reg = 0; reg < 4; ++reg) pk[reg] = (__bf16)(acc[mf][nf][reg] + bb);
                *reinterpret_cast<bf16x4*>(Vblk + (size_t)(bi * NKV + hh) * (S_LEN * HD)
                                           + (s >> 6) * 4096 + dd * 64 + (s & 63)) = pk;
            }
        } else {
#pragma unroll
            for (int mf = 0; mf < 2; ++mf)
#pragma unroll
                for (int reg = 0; reg < 4; ++reg) {
                    int m = m0 + wr * 32 + mf * 16 + g * 4 + reg;
                    int bi = m >> 11, s = m & 2047;
                    __bf16 o = (__bf16)(acc[mf][nf][reg] + bb);
                    if (mode == 0)
                        Qb[((size_t)(bi * NH + hh) * S_LEN + s) * HD + dd] = o;
                    else
                        Kb[((size_t)(bi * NKV + hh) * S_LEN + s) * HD + dd] = o;
                }
        }
    }
}

// ---------- sliding-window flash attention (unchanged from r5/r6) ----------
__global__ __launch_bounds__(256, 3) void attn_kernel(const __bf16* __restrict__ Qb,
                                                      const __bf16* __restrict__ Kb,
                                                      const __bf16* __restrict__ Vblk,
                                                      __bf16* __restrict__ ctx) {
    __shared__ __align__(16) __bf16 Ks[2][64 * 64];      // [buf][row=key][d]  8KB each
    __shared__ __align__(16) __bf16 Vs[2][64 * 64];      // [buf][row=d][key]  8KB each
    __shared__ __align__(16) __bf16 Plds[4][16 * PPAD];  // per-wave P [q=16][k=64 pad]
    const int tid = threadIdx.x;
    const int lane = tid & 63, w = tid >> 6;
    const int r = lane & 15, g = lane >> 4;
    const int q0 = blockIdx.x * 64;
    const int h = blockIdx.y, b = blockIdx.z;
    const int kvh = h >> 2;
    const __bf16* Qw = Qb + ((size_t)(b * NH + h) * S_LEN + q0 + w * 16) * HD;
    const __bf16* Kh = Kb + (size_t)(b * NKV + kvh) * S_LEN * HD;
    const __bf16* Vh = Vblk + (size_t)(b * NKV + kvh) * S_LEN * HD;
    __bf16* Pw = &Plds[w][0];

    const int n0s = w * 128 + lane;
    const int n1s = n0s + 64;
    const int srcoff0 = (n0s >> 3) * 64 + (((n0s & 7) ^ ((n0s >> 3) & 7)) * 8);
    const int srcoff1 = (n1s >> 3) * 64 + (((n1s & 7) ^ ((n1s >> 3) & 7)) * 8);
    const int dst0 = (w * 2) * 512;
    const int dst1 = dst0 + 512;

    auto stage = [&](int buf, int kbase) {
        const __bf16* Kt = Kh + (size_t)kbase * 64;
        const __bf16* Vt = Vh + (size_t)kbase * 64;
        gload16(Kt + srcoff0, &Ks[buf][dst0]);
        gload16(Kt + srcoff1, &Ks[buf][dst1]);
        gload16(Vt + srcoff0, &Vs[buf][dst0]);
        gload16(Vt + srcoff1, &Vs[buf][dst1]);
    };

    const int swz0 = ((0 * 4 + g) ^ (r & 7)) * 8;
    const int swz1 = ((1 * 4 + g) ^ (r & 7)) * 8;

    bf16x8 qf[2];
#pragma unroll
    for (int kk = 0; kk < 2; ++kk)
        qf[kk] = *(const bf16x8*)(Qw + r * 64 + kk * 32 + g * 8);

    f32x4 z = {0.f, 0.f, 0.f, 0.f};
    f32x4 o[4];
#pragma unroll
    for (int i = 0; i < 4; ++i) o[i] = z;
    float psum = 0.f;

    const float SC = 0.18033688011112042f;   // D^-0.5 * log2(e)
    const int iq = q0 + w * 16 + r;

    auto tile = [&](int buf, int kbase, bool masked) {
        const __bf16* Kl = &Ks[buf][0];
        const __bf16* Vl = &Vs[buf][0];
        bf16x8 kf[4][2];
#pragma unroll
        for (int nf = 0; nf < 4; ++nf) {
            kf[nf][0] = *(const bf16x8*)(Kl + nf * 1024 + r * 64 + swz0);
            kf[nf][1] = *(const bf16x8*)(Kl + nf * 1024 + r * 64 + swz1);
        }
        f32x4 sa[4];
#pragma unroll
        for (int nf = 0; nf < 4; ++nf) sa[nf] = z;
#pragma unroll
        for (int nf = 0; nf < 4; ++nf)
#pragma unroll
            for (int kk = 0; kk < 2; ++kk)
                sa[nf] = __builtin_amdgcn_mfma_f32_16x16x32_bf16(kf[nf][kk], qf[kk], sa[nf], 0, 0, 0);
#pragma unroll
        for (int nf = 0; nf < 4; ++nf) {
            int jb = kbase + nf * 16 + g * 4;
            bf16x4 pk;
#pragma unroll
            for (int reg = 0; reg < 4; ++reg) {
                float x = sa[nf][reg] * SC;
                if (masked) {
                    uint32_t d = (uint32_t)(iq - (jb + reg));
                    x = (d <= (uint32_t)WIN) ? x : -1e30f;
                }
                float e = fast_exp2(x);
                psum += e;
                pk[reg] = (__bf16)e;
            }
            *reinterpret_cast<bf16x4*>(Pw + r * PPAD + nf * 16 + g * 4) = pk;
        }
        bf16x8 vf[4][2];
#pragma unroll
        for (int nf2 = 0; nf2 < 4; ++nf2) {
            vf[nf2][0] = *(const bf16x8*)(Vl + nf2 * 1024 + r * 64 + swz0);
            vf[nf2][1] = *(const bf16x8*)(Vl + nf2 * 1024 + r * 64 + swz1);
        }
#pragma unroll
        for (int kk2 = 0; kk2 < 2; ++kk2) {
            bf16x8 pa = *(const bf16x8*)(Pw + r * PPAD + kk2 * 32 + g * 8);
#pragma unroll
            for (int nf2 = 0; nf2 < 4; ++nf2)
                o[nf2] = __builtin_amdgcn_mfma_f32_16x16x32_bf16(vf[nf2][kk2], pa, o[nf2], 0, 0, 0);
        }
    };

    const int kb0 = (q0 >= 256) ? (q0 - 256) : 0;
    const int nt = (q0 - kb0) / 64 + 1;
    stage(0, kb0);
    __syncthreads();
    for (int t = 0; t < nt; ++t) {
        int kbase = kb0 + t * 64;
        if (t + 1 < nt) stage((t + 1) & 1, kbase + 64);
        bool masked = (kbase == q0) || (q0 >= 256 && t == 0);
        tile(t & 1, kbase, masked);
        __syncthreads();
    }

    psum += __shfl_xor(psum, 16, 64);
    psum += __shfl_xor(psum, 32, 64);
    float linv = 1.0f / psum;

    int s = q0 + w * 16 + r;
#pragma unroll
    for (int nf2 = 0; nf2 < 4; ++nf2) {
        bf16x4 pk;
#pragma unroll
        for (int reg = 0; reg < 4; ++reg) pk[reg] = (__bf16)(o[nf2][reg] * linv);
        *reinterpret_cast<bf16x4*>(ctx + ((size_t)(b * S_LEN + s)) * EMB + h * 64 + nf2 * 16 + g * 4) = pk;
    }
}

// ---------- output projection ----------
// 1D grid 512, XCD-swizzled
__global__ __launch_bounds__(256, 3) void gemm_out_kernel(const __bf16* __restrict__ ctxb,
                                                          const __bf16* __restrict__ wot,
                                                          const float* __restrict__ bo,
                                                          float* __restrict__ out) {
    __shared__ __align__(16) __bf16 As[2][64 * 64];
    __shared__ __align__(16) __bf16 Bs[2][128 * 64];
    int tid = threadIdx.x;
    int wg = (blockIdx.x & 7) * 64 + (blockIdx.x >> 3);   // 512 = 8 XCD x 64
    int n0 = (wg % 8) * 128, m0 = (wg / 8) * 64;

    f32x4 acc[2][4];
    f32x4 z = {0.f, 0.f, 0.f, 0.f};
#pragma unroll
    for (int i = 0; i < 2; ++i)
#pragma unroll
        for (int j = 0; j < 4; ++j) acc[i][j] = z;

    gemm_core64(ctxb, wot, EMB, m0, n0, As, Bs, acc, tid);

    const int lane = tid & 63, w = tid >> 6;
    const int wr = w >> 1, wc = w & 1, r = lane & 15, g = lane >> 4;
#pragma unroll
    for (int nf = 0; nf < 4; ++nf) {
        int n = n0 + wc * 64 + nf * 16 + r;
        float bb = bo[n];
#pragma unroll
        for (int mf = 0; mf < 2; ++mf)
#pragma unroll
            for (int reg = 0; reg < 4; ++reg) {
                int m = m0 + wr * 32 + mf * 16 + g * 4 + reg;
                out[(size_t)m * EMB + n] = acc[mf][nf][reg] + bb;
            }
    }
}

// ---------- launch ----------
extern "C" void kernel_launch(void* const* d_in, const int* in_sizes, int n_in,
                              void* d_out, int out_size, void* d_ws, size_t ws_size,
                              hipStream_t stream) {
    const float* x  = (const float*)d_in[0];
    const float* wq = (const float*)d_in[1];
    const float* bq = (const float*)d_in[2];
    const float* wk = (const float*)d_in[3];
    const float* bk = (const float*)d_in[4];
    const float* wv = (const float*)d_in[5];
    const float* bv = (const float*)d_in[6];
    const float* wo = (const float*)d_in[7];
    const float* bo = (const float*)d_in[8];
    float* out = (float*)d_out;

    char* ws = (char*)d_ws;
    __bf16* xb   = (__bf16*)ws;          ws += (size_t)MROWS * EMB * 2;           // 8 MB
    __bf16* wqt  = (__bf16*)ws;          ws += (size_t)EMB * EMB * 2;             // 2 MB
    __bf16* wkt  = (__bf16*)ws;          ws += (size_t)256 * EMB * 2;             // 0.5 MB
    __bf16* wvt  = (__bf16*)ws;          ws += (size_t)256 * EMB * 2;             // 0.5 MB
    __bf16* wot  = (__bf16*)ws;          ws += (size_t)EMB * EMB * 2;             // 2 MB
    __bf16* Qb   = (__bf16*)ws;          ws += (size_t)NB * NH * S_LEN * HD * 2;  // 8 MB
    __bf16* Kb   = (__bf16*)ws;          ws += (size_t)NB * NKV * S_LEN * HD * 2; // 2 MB
    __bf16* Vblk = (__bf16*)ws;          ws += (size_t)NB * NKV * S_LEN * HD * 2; // 2 MB
    __bf16* ctx  = (__bf16*)ws;          ws += (size_t)MROWS * EMB * 2;           // 8 MB

    prep_kernel<<<3328, 256, 0, stream>>>(x, wq, wk, wv, wo,
                                          (u16*)xb, (u16*)wqt, (u16*)wkt, (u16*)wvt, (u16*)wot);
    gemm_qkv_kernel<<<768, 256, 0, stream>>>(xb, wqt, wkt, wvt, bq, bk, bv, Qb, Kb, Vblk);
    attn_kernel<<<dim3(32, 16, 2), 256, 0, stream>>>(Qb, Kb, Vblk, ctx);
    gemm_out_kernel<<<512, 256, 0, stream>>>(ctx, wot, bo, out);
}